// Round 5
// baseline (201.111 us; speedup 1.0000x reference)
//
#include <hip/hip_runtime.h>
#include <cstdint>
#include <cstddef>

#define D_MODEL 256
#define D_STATE 64
#define HEADDIM 64
#define D_INNER 512
#define NHEADS 8
#define D_XBC 640
#define NPROJ 1160
#define ZXW 1152   /* bf16 zxbc row width (z + xBC) */
#define BATCH 64
#define SEQ 250
#define ROWS (BATCH * SEQ) /* 16000 */
#define KIN 240
#define KPAD 256
#define NPAD 1280  /* padded to 10x128 col-panels for the 128x128-tile gemm1 */

typedef __bf16 bf16x8 __attribute__((ext_vector_type(8)));
typedef float f32x4 __attribute__((ext_vector_type(4)));

typedef __attribute__((address_space(1))) const void gv_t;
typedef __attribute__((address_space(3))) void lv_t;

__device__ __forceinline__ float readlane_f(float v, int lane) {
    return __uint_as_float(__builtin_amdgcn_readlane(__float_as_uint(v), lane));
}
__device__ __forceinline__ float silu_f(float x) { return x * (1.f / (1.f + __expf(-x))); }
__device__ __forceinline__ unsigned short bf16_rne(float f) {
    unsigned int u = __float_as_uint(f);
    u += 0x7fff + ((u >> 16) & 1);
    return (unsigned short)(u >> 16);
}
__device__ __forceinline__ float bf2f(unsigned short u) {
    return __uint_as_float(((unsigned int)u) << 16);
}
__device__ __forceinline__ unsigned int pack2(float a, float b) {
    return (unsigned int)bf16_rne(a) | ((unsigned int)bf16_rne(b) << 16);
}

// ---------------------------------------------------------------------------
// Kernel 0: cast_all — x -> a_bf [16000][256], W_in -> bt_bf [1280][256] (T),
// W_out -> wt_bf [256][512] (T). One launch for all three.
// ---------------------------------------------------------------------------
#define NA (ROWS * KPAD)
#define NB (NPAD * KPAD)
#define NW (D_MODEL * D_INNER)
__global__ __launch_bounds__(256) void cast_all_kernel(const float* __restrict__ x,
                                                       const float* __restrict__ Win,
                                                       const float* __restrict__ Wout,
                                                       unsigned short* __restrict__ a_bf,
                                                       unsigned short* __restrict__ bt_bf,
                                                       unsigned short* __restrict__ wt_bf) {
    int idx = blockIdx.x * 256 + threadIdx.x;
    if (idx < NA) {
        int row = idx >> 8, c = idx & 255;
        float v = (c < KIN) ? x[row * KIN + c] : 0.f;
        a_bf[idx] = bf16_rne(v);
    } else if (idx < NA + NB) {
        int r = idx - NA;
        int n = r >> 8, k = r & 255;
        float v = (n < NPROJ && k < KIN) ? Win[k * NPROJ + n] : 0.f;
        bt_bf[r] = bf16_rne(v);
    } else if (idx < NA + NB + NW) {
        int r = idx - NA - NB;
        int n = r & 255, k = r >> 8;
        wt_bf[n * D_INNER + k] = bf16_rne(Wout[k * D_MODEL + n]);
    }
}

// ---------------------------------------------------------------------------
// Kernel 1: gemm1 — m97-structure: 128x128 tile, BK=32, linear LDS,
// global_load_lds width=16 staging. Grid 10 x 125. Writes bf16 zxbc
// (cols 0..1151) + fp32 dtraw (cols 1152..1159); cols >=1160 discarded.
// ---------------------------------------------------------------------------
__global__ __launch_bounds__(256) void gemm1_mfma(const unsigned short* __restrict__ A,
                                                  const unsigned short* __restrict__ Bt,
                                                  unsigned short* __restrict__ Czx,
                                                  float* __restrict__ dtraw) {
    __shared__ unsigned short As[128 * 32];
    __shared__ unsigned short Bs[128 * 32];
    const int tid = threadIdx.x;
    const int lane = tid & 63, wave = tid >> 6;
    const int wm = wave >> 1, wn = wave & 1;
    const int q = lane >> 4, l15 = lane & 15;
    const int rowBase = blockIdx.y * 128, colBase = blockIdx.x * 128;
    f32x4 acc[4][4] = {};

    const int sr = tid >> 2;          // staging row 0..63
    const int sc = (tid & 3) * 8;     // staging col (bf16) 0,8,16,24

    const unsigned short* gA = A + (size_t)(rowBase + sr) * KPAD + sc;
    const unsigned short* gB = Bt + (size_t)(colBase + sr) * KPAD + sc;
    unsigned short* lA = &As[sr * 32 + sc];   // wave-uniform base + lane*16B
    unsigned short* lB = &Bs[sr * 32 + sc];

    for (int k0 = 0; k0 < KPAD; k0 += 32) {
        __builtin_amdgcn_global_load_lds((gv_t*)(gA + k0), (lv_t*)lA, 16, 0, 0);
        __builtin_amdgcn_global_load_lds((gv_t*)(gA + 64 * KPAD + k0),
                                         (lv_t*)(lA + 64 * 32), 16, 0, 0);
        __builtin_amdgcn_global_load_lds((gv_t*)(gB + k0), (lv_t*)lB, 16, 0, 0);
        __builtin_amdgcn_global_load_lds((gv_t*)(gB + 64 * KPAD + k0),
                                         (lv_t*)(lB + 64 * 32), 16, 0, 0);
        __syncthreads();

        bf16x8 bfr[4];
#pragma unroll
        for (int nt = 0; nt < 4; nt++)
            bfr[nt] = *(const bf16x8*)&Bs[(wn * 64 + nt * 16 + l15) * 32 + q * 8];
#pragma unroll
        for (int mt = 0; mt < 4; mt++) {
            bf16x8 afr = *(const bf16x8*)&As[(wm * 64 + mt * 16 + l15) * 32 + q * 8];
#pragma unroll
            for (int nt = 0; nt < 4; nt++)
                acc[mt][nt] = __builtin_amdgcn_mfma_f32_16x16x32_bf16(afr, bfr[nt],
                                                                      acc[mt][nt], 0, 0, 0);
        }
        __syncthreads();
    }
#pragma unroll
    for (int mt = 0; mt < 4; mt++) {
        int grow0 = rowBase + wm * 64 + mt * 16 + q * 4;
#pragma unroll
        for (int nt = 0; nt < 4; nt++) {
            int gcol = colBase + wn * 64 + nt * 16 + l15;
            if (gcol < ZXW) {
#pragma unroll
                for (int reg = 0; reg < 4; reg++) {
                    unsigned int u = bf16_rne(acc[mt][nt][reg]);
                    unsigned int partner = (unsigned int)__shfl_xor((int)u, 1, 64);
                    if ((l15 & 1) == 0)
                        *(unsigned int*)&Czx[(size_t)(grow0 + reg) * ZXW + gcol] =
                            u | (partner << 16);
                }
            } else if (gcol < NPROJ) {
#pragma unroll
                for (int reg = 0; reg < 4; reg++)
                    dtraw[(size_t)(grow0 + reg) * NHEADS + (gcol - ZXW)] = acc[mt][nt][reg];
            }
        }
    }
}

// ---------------------------------------------------------------------------
// Kernel 2: scan_fused v2 — one block per (b,h); conv4+SiLU fused into the
// staging phase (reads zxbc directly; conv kernel deleted). 4 chunks
// sequential; inter-chunk state h in f32 registers + bf16 LDS mirror.
// Per chunk: stage In[67][192] (x_h|B|C) -> per-channel rolling conv ->
// C_l[t][n], BP_l[t][n], XT_l[p][t], B kept packed in regs for BwT.
// dt softplus computed inline from dtraw.
// ---------------------------------------------------------------------------
#define LSTR 72
#define INSTR 200
__global__ __launch_bounds__(256) void scan_fused(const unsigned short* __restrict__ zxbc,
                                                  const float* __restrict__ dtraw,
                                                  const float* __restrict__ conv_w,
                                                  const float* __restrict__ conv_b,
                                                  const float* __restrict__ dt_bias,
                                                  const float* __restrict__ A_log,
                                                  const float* __restrict__ Dvec,
                                                  unsigned short* __restrict__ yout_bf) {
    __shared__ unsigned short C_l[64 * LSTR];   // C [t][n], then (post-S3) BwT [n][t]
    __shared__ unsigned short BP_l[64 * LSTR];  // B [t][n], then (post-S3) P [t][s]
    __shared__ unsigned short XT_l[64 * LSTR];  // x^T [p][t]
    __shared__ unsigned short H_l[64 * LSTR];   // h_{c-1} bf16 [p][n]
    __shared__ unsigned short In_l[67 * INSTR]; // pre-conv zxbc rows, 192 ch
    __shared__ float Wk_l[4][INSTR];            // conv weights [k][local ch]
    __shared__ float Bi_l[192];                 // conv bias
    __shared__ float cs_s[64], dts_s[64], fws_s[64];
    __shared__ float tot_s;

    const int bh = blockIdx.x;
    const int b = bh >> 3, h = bh & 7;
    const int tid = threadIdx.x;
    const int lane = tid & 63, w = tid >> 6;
    const int q = lane >> 4, l15 = lane & 15;
    const float A = -__expf(A_log[h]);
    const float Dh = Dvec[h];
    const float dtb = dt_bias[h];

    // stage conv weights/bias once (local ch: 0..63 x_h, 64..127 B, 128..191 C)
    for (int i = tid; i < 192; i += 256) {
        int xbc = (i < 64) ? (h * 64 + i) : (448 + i);  // 64->512(B), 128->576(C)
        Bi_l[i] = conv_b[xbc];
#pragma unroll
        for (int k = 0; k < 4; k++) Wk_l[k][i] = conv_w[xbc * 4 + k];
    }

    f32x4 h_acc[4] = {};  // h[p][n]: rows p=w*16+q*4+rr, cols n=nt*16+l15

    for (int c = 0; c < 4; ++c) {
        const int t0 = c * 64;
        __syncthreads();  // S0: weights visible (c=0); prev-chunk LDS reads done (c>0)

        // ---- stage In: rows t0-3..t0+63, cols x_h(64)|B(64)|C(64) ----
        for (int i = tid; i < 67 * 24; i += 256) {
            int r = i / 24, s = i - r * 24;
            int tg = t0 - 3 + r;
            int colg = (s < 8) ? (D_INNER + h * 64 + s * 8) : (D_INNER + 512 + (s - 8) * 8);
            uint4 v = {0, 0, 0, 0};
            if (tg >= 0 && tg < SEQ)
                v = *(const uint4*)&zxbc[(size_t)(b * SEQ + tg) * ZXW + colg];
            *(uint4*)&In_l[r * INSTR + s * 8] = v;
        }
        // ---- dt prescan (w==0): softplus inline ----
        if (w == 0) {
            int t = lane;
            float dtv = 0.f;
            if (t0 + t < SEQ) {
                float v = dtraw[(size_t)(b * SEQ + t0 + t) * NHEADS + h] + dtb;
                dtv = (v > 20.f) ? v : __logf(1.f + __expf(v));
            }
            float csv = dtv * A;
#pragma unroll
            for (int o = 1; o < 64; o <<= 1) {
                float u = __shfl_up(csv, o, 64);
                if (lane >= o) csv += u;
            }
            float tot = readlane_f(csv, 63);
            cs_s[t] = csv;
            dts_s[t] = dtv;
            fws_s[t] = dtv * __expf(tot - csv);
            if (lane == 0) tot_s = tot;
        }
        __syncthreads();  // S_in

        // ---- conv phase: lane = channel, wave = 16-t slice ----
        const int cA = lane;
        const int base = w * 16;
        unsigned int bpk[8];  // raw B bf16-packed (for BwT post-S3)
        {
            const float wx0 = Wk_l[0][cA], wx1 = Wk_l[1][cA], wx2 = Wk_l[2][cA],
                        wx3 = Wk_l[3][cA], bx = Bi_l[cA];
            const float wb0 = Wk_l[0][64 + cA], wb1 = Wk_l[1][64 + cA],
                        wb2 = Wk_l[2][64 + cA], wb3 = Wk_l[3][64 + cA], bb = Bi_l[64 + cA];
            const float wc0 = Wk_l[0][128 + cA], wc1 = Wk_l[1][128 + cA],
                        wc2 = Wk_l[2][128 + cA], wc3 = Wk_l[3][128 + cA], bc = Bi_l[128 + cA];
            float x0 = bf2f(In_l[(base + 0) * INSTR + cA]);
            float x1 = bf2f(In_l[(base + 1) * INSTR + cA]);
            float x2 = bf2f(In_l[(base + 2) * INSTR + cA]);
            float b0 = bf2f(In_l[(base + 0) * INSTR + 64 + cA]);
            float b1 = bf2f(In_l[(base + 1) * INSTR + 64 + cA]);
            float b2 = bf2f(In_l[(base + 2) * INSTR + 64 + cA]);
            float c0v = bf2f(In_l[(base + 0) * INSTR + 128 + cA]);
            float c1v = bf2f(In_l[(base + 1) * INSTR + 128 + cA]);
            float c2v = bf2f(In_l[(base + 2) * INSTR + 128 + cA]);
            unsigned int xu[8];
            unsigned int lox = 0, lob = 0;
#pragma unroll
            for (int j = 0; j < 16; j++) {
                const int t = base + j;
                const bool valid = (t0 + t < SEQ);
                float x3 = bf2f(In_l[(t + 3) * INSTR + cA]);
                float ax = fmaf(wx3, x3, fmaf(wx2, x2, fmaf(wx1, x1, fmaf(wx0, x0, bx))));
                float sx = valid ? silu_f(ax) : 0.f;
                x0 = x1; x1 = x2; x2 = x3;
                float b3 = bf2f(In_l[(t + 3) * INSTR + 64 + cA]);
                float ab = fmaf(wb3, b3, fmaf(wb2, b2, fmaf(wb1, b1, fmaf(wb0, b0, bb))));
                float sb = valid ? silu_f(ab) : 0.f;
                b0 = b1; b1 = b2; b2 = b3;
                float c3v = bf2f(In_l[(t + 3) * INSTR + 128 + cA]);
                float ac = fmaf(wc3, c3v, fmaf(wc2, c2v, fmaf(wc1, c1v, fmaf(wc0, c0v, bc))));
                float sc = valid ? silu_f(ac) : 0.f;
                c0v = c1v; c1v = c2v; c2v = c3v;
                unsigned int ux = bf16_rne(sx);
                if (j & 1) xu[j >> 1] = lox | (ux << 16); else lox = ux;
                unsigned int ub = bf16_rne(sb);
                unsigned int pb = (unsigned int)__shfl_xor((int)ub, 1, 64);
                if (!(cA & 1)) *(unsigned int*)&BP_l[t * LSTR + cA] = ub | (pb << 16);
                if (j & 1) bpk[j >> 1] = lob | (ub << 16); else lob = ub;
                unsigned int uc = bf16_rne(sc);
                unsigned int pc = (unsigned int)__shfl_xor((int)uc, 1, 64);
                if (!(cA & 1)) *(unsigned int*)&C_l[t * LSTR + cA] = uc | (pc << 16);
            }
            uint4 xa0, xa1;
            xa0.x = xu[0]; xa0.y = xu[1]; xa0.z = xu[2]; xa0.w = xu[3];
            xa1.x = xu[4]; xa1.y = xu[5]; xa1.z = xu[6]; xa1.w = xu[7];
            *(uint4*)&XT_l[cA * LSTR + base] = xa0;
            *(uint4*)&XT_l[cA * LSTR + base + 8] = xa1;
        }
        __syncthreads();  // S1

        // ---- G = C.B^T and y_inter = C.h_{c-1}^T ----
        f32x4 g[4] = {};
        f32x4 yi[4] = {};
#pragma unroll
        for (int k0 = 0; k0 < 64; k0 += 32) {
            bf16x8 ca = *(const bf16x8*)&C_l[(w * 16 + l15) * LSTR + k0 + q * 8];
#pragma unroll
            for (int nt = 0; nt < 4; nt++) {
                bf16x8 bb2 = *(const bf16x8*)&BP_l[(nt * 16 + l15) * LSTR + k0 + q * 8];
                g[nt] = __builtin_amdgcn_mfma_f32_16x16x32_bf16(ca, bb2, g[nt], 0, 0, 0);
            }
            if (c > 0) {
#pragma unroll
                for (int nt = 0; nt < 4; nt++) {
                    bf16x8 hb = *(const bf16x8*)&H_l[(nt * 16 + l15) * LSTR + k0 + q * 8];
                    yi[nt] = __builtin_amdgcn_mfma_f32_16x16x32_bf16(ca, hb, yi[nt], 0, 0, 0);
                }
            }
        }
        __syncthreads();  // S3

        {   // C_l <- BwT [n][t]: raw B (bpk) scaled by fws
            unsigned short tmp[16];
#pragma unroll
            for (int j = 0; j < 8; j++) {
                unsigned int v = bpk[j];
                tmp[2 * j] = bf16_rne(bf2f((unsigned short)(v & 0xffff)) * fws_s[base + 2 * j]);
                tmp[2 * j + 1] = bf16_rne(bf2f((unsigned short)(v >> 16)) * fws_s[base + 2 * j + 1]);
            }
            *(uint4*)&C_l[cA * LSTR + base] = *(uint4*)&tmp[0];
            *(uint4*)&C_l[cA * LSTR + base + 8] = *(uint4*)&tmp[8];
        }
#pragma unroll
        for (int nt = 0; nt < 4; nt++) {   // BP_l <- P
#pragma unroll
            for (int rr = 0; rr < 4; rr++) {
                int t = w * 16 + q * 4 + rr;
                int s = nt * 16 + l15;
                float pv = 0.f;
                if (s <= t) {
                    pv = g[nt][rr] * __expf(cs_s[t] - cs_s[s]) * dts_s[s];
                    if (s == t) pv += Dh;
                }
                unsigned int u = bf16_rne(pv);
                unsigned int partner = (unsigned int)__shfl_xor((int)u, 1, 64);
                if ((l15 & 1) == 0)
                    *(unsigned int*)&BP_l[t * LSTR + nt * 16 + l15] = u | (partner << 16);
            }
        }
        __syncthreads();  // S4

        // ---- y_intra = P.x^T ----
        f32x4 y[4] = {};
#pragma unroll
        for (int k0 = 0; k0 < 64; k0 += 32) {
            bf16x8 pa = *(const bf16x8*)&BP_l[(w * 16 + l15) * LSTR + k0 + q * 8];
#pragma unroll
            for (int nt = 0; nt < 4; nt++) {
                bf16x8 xb = *(const bf16x8*)&XT_l[(nt * 16 + l15) * LSTR + k0 + q * 8];
                y[nt] = __builtin_amdgcn_mfma_f32_16x16x32_bf16(pa, xb, y[nt], 0, 0, 0);
            }
        }
        if (c < 3) {
            f32x4 st[4] = {};
#pragma unroll
            for (int k0 = 0; k0 < 64; k0 += 32) {
                bf16x8 xa = *(const bf16x8*)&XT_l[(w * 16 + l15) * LSTR + k0 + q * 8];
#pragma unroll
                for (int nt = 0; nt < 4; nt++) {
                    bf16x8 bwb = *(const bf16x8*)&C_l[(nt * 16 + l15) * LSTR + k0 + q * 8];
                    st[nt] = __builtin_amdgcn_mfma_f32_16x16x32_bf16(xa, bwb, st[nt], 0, 0, 0);
                }
            }
            const float decay = __expf(tot_s);
#pragma unroll
            for (int nt = 0; nt < 4; nt++) {
                h_acc[nt] = st[nt] + decay * h_acc[nt];
#pragma unroll
                for (int rr = 0; rr < 4; rr++) {
                    unsigned int u = bf16_rne(h_acc[nt][rr]);
                    unsigned int partner = (unsigned int)__shfl_xor((int)u, 1, 64);
                    if ((l15 & 1) == 0)
                        *(unsigned int*)&H_l[(w * 16 + q * 4 + rr) * LSTR + nt * 16 + l15] =
                            u | (partner << 16);
                }
            }
        }
#pragma unroll
        for (int nt = 0; nt < 4; nt++)
#pragma unroll
            for (int rr = 0; rr < 4; rr++) {
                int t = w * 16 + q * 4 + rr;
                if (t0 + t < SEQ) {
                    int p = nt * 16 + l15;
                    float yv = y[nt][rr];
                    if (c > 0) yv += __expf(cs_s[t]) * yi[nt][rr];
                    unsigned int u = bf16_rne(yv);
                    unsigned int partner = (unsigned int)__shfl_xor((int)u, 1, 64);
                    if ((l15 & 1) == 0)
                        *(unsigned int*)&yout_bf[(size_t)(b * SEQ + t0 + t) * D_INNER +
                                                 h * HEADDIM + p] = u | (partner << 16);
                }
            }
    }
}

// ---------------------------------------------------------------------------
// Kernel 3: gemm2_fused — out = selu( rms_r * ((y*silu(z)*norm_w) @ W^T) ).
// R2-proven 32-row/500-block version (grid must stay >= 2x CU count).
// ---------------------------------------------------------------------------
#define SA 40
__global__ __launch_bounds__(256) void gemm2_fused(const unsigned short* __restrict__ yout_bf,
                                                   const unsigned short* __restrict__ zxbc,
                                                   const unsigned short* __restrict__ Bt,
                                                   const float* __restrict__ norm_w,
                                                   float* __restrict__ out) {
    __shared__ unsigned short As2[32 * SA];
    __shared__ unsigned short Bs2[256 * SA];
    __shared__ float rms_s[32];
    const int tid = threadIdx.x;
    const int lane = tid & 63;
    const int wn = tid >> 6;               // wave -> 64-col slice
    const int q = lane >> 4, l15 = lane & 15;
    const int rowBase = blockIdx.x * 32;
    f32x4 acc[2][4] = {};

    const int tr = tid >> 3;               // staging row 0..31
    const int tk = (tid & 7) * 4;          // staging k-offset 0..28

    const unsigned short* yrow = yout_bf + (size_t)(rowBase + tr) * D_INNER + tk;
    const unsigned short* zrow = zxbc + (size_t)(rowBase + tr) * ZXW + tk;
    float ssq = 0.f;

    for (int k0 = 0; k0 < D_INNER; k0 += 32) {
        // ---- A: u = y*silu(z)*norm_w, accumulate g^2 ----
        uint2 yp = *(const uint2*)&yrow[k0];
        uint2 zp = *(const uint2*)&zrow[k0];
        float4 nw = *(const float4*)&norm_w[k0 + tk];
        const unsigned short* ys = (const unsigned short*)&yp;
        const unsigned short* zs = (const unsigned short*)&zp;
        float g0 = bf2f(ys[0]) * silu_f(bf2f(zs[0]));
        float g1 = bf2f(ys[1]) * silu_f(bf2f(zs[1]));
        float g2 = bf2f(ys[2]) * silu_f(bf2f(zs[2]));
        float g3 = bf2f(ys[3]) * silu_f(bf2f(zs[3]));
        ssq = fmaf(g0, g0, ssq);
        ssq = fmaf(g1, g1, ssq);
        ssq = fmaf(g2, g2, ssq);
        ssq = fmaf(g3, g3, ssq);
        uint2 pk;
        pk.x = pack2(g0 * nw.x, g1 * nw.y);
        pk.y = pack2(g2 * nw.z, g3 * nw.w);
        *(uint2*)&As2[tr * SA + tk] = pk;
        // ---- B: col `tid`, 32 k-shorts ----
        const unsigned short* brow = Bt + (size_t)tid * D_INNER + k0;
        *(uint4*)&Bs2[tid * SA + 0] = *(const uint4*)&brow[0];
        *(uint4*)&Bs2[tid * SA + 8] = *(const uint4*)&brow[8];
        *(uint4*)&Bs2[tid * SA + 16] = *(const uint4*)&brow[16];
        *(uint4*)&Bs2[tid * SA + 24] = *(const uint4*)&brow[24];
        __syncthreads();

        bf16x8 bfr[4];
#pragma unroll
        for (int nt = 0; nt < 4; nt++)
            bfr[nt] = *(const bf16x8*)&Bs2[(wn * 64 + nt * 16 + l15) * SA + q * 8];
#pragma unroll
        for (int mt = 0; mt < 2; mt++) {
            bf16x8 afr = *(const bf16x8*)&As2[(mt * 16 + l15) * SA + q * 8];
#pragma unroll
            for (int nt = 0; nt < 4; nt++)
                acc[mt][nt] = __builtin_amdgcn_mfma_f32_16x16x32_bf16(afr, bfr[nt],
                                                                      acc[mt][nt], 0, 0, 0);
        }
        __syncthreads();
    }
    // per-row rms: reduce ssq over the 8 lanes (tid&7) that share row tr
    ssq += __shfl_xor(ssq, 1, 64);
    ssq += __shfl_xor(ssq, 2, 64);
    ssq += __shfl_xor(ssq, 4, 64);
    if ((tid & 7) == 0) rms_s[tr] = rsqrtf(ssq * (1.f / 512.f) + 1e-5f);
    __syncthreads();

    const float SC = 1.0507009873554805f, AL = 1.6732632423543772f;
#pragma unroll
    for (int mt = 0; mt < 2; mt++) {
        int lrow0 = mt * 16 + q * 4;
#pragma unroll
        for (int nt = 0; nt < 4; nt++) {
            int gcol = wn * 64 + nt * 16 + l15;
            if (gcol < 240) {
#pragma unroll
                for (int reg = 0; reg < 4; reg++) {
                    float v = acc[mt][nt][reg] * rms_s[lrow0 + reg];
                    v = (v > 0.f) ? SC * v : SC * AL * (__expf(v) - 1.f);
                    out[(size_t)(rowBase + lrow0 + reg) * 240 + gcol] = v;
                }
            }
        }
    }
}

// ---------------------------------------------------------------------------
extern "C" void kernel_launch(void* const* d_in, const int* in_sizes, int n_in,
                              void* d_out, int out_size, void* d_ws, size_t ws_size,
                              hipStream_t stream) {
    const float* x = (const float*)d_in[0];
    const float* W_in = (const float*)d_in[1];
    const float* conv_w = (const float*)d_in[2];
    const float* conv_b = (const float*)d_in[3];
    const float* A_log = (const float*)d_in[4];
    const float* dt_bias = (const float*)d_in[5];
    const float* Dv = (const float*)d_in[6];
    const float* norm_w = (const float*)d_in[7];
    const float* W_out = (const float*)d_in[8];
    float* out = (float*)d_out;

    unsigned short* us = (unsigned short*)d_ws;
    unsigned short* zxbc_bf = us;                              // 16000*1152
    unsigned short* yout_bf = zxbc_bf + (size_t)ROWS * ZXW;    // 16000*512
    unsigned short* bt_bf = yout_bf + (size_t)ROWS * D_INNER;  // 1280*256
    unsigned short* wt_bf = bt_bf + (size_t)NPAD * KPAD;       // 256*512
    float* dtraw = (float*)(wt_bf + (size_t)D_MODEL * D_INNER);  // 16000*8
    unsigned short* a_bf = (unsigned short*)(dtraw + (size_t)ROWS * NHEADS);  // 16000*256

    int cast_total = NA + NB + NW;
    cast_all_kernel<<<dim3((cast_total + 255) / 256), 256, 0, stream>>>(x, W_in, W_out,
                                                                        a_bf, bt_bf, wt_bf);

    gemm1_mfma<<<dim3(NPAD / 128, ROWS / 128), 256, 0, stream>>>(a_bf, bt_bf, zxbc_bf, dtraw);

    scan_fused<<<dim3(BATCH * NHEADS), 256, 0, stream>>>(zxbc_bf, dtraw, conv_w, conv_b,
                                                         dt_bias, A_log, Dv, yout_bf);

    gemm2_fused<<<dim3(ROWS / 32), 256, 0, stream>>>(yout_bf, zxbc_bf, wt_bf, norm_w, out);
}

// Round 7
// 192.354 us; speedup vs baseline: 1.0455x; 1.0455x over previous
//
#include <hip/hip_runtime.h>
#include <cstdint>
#include <cstddef>

#define D_MODEL 256
#define D_STATE 64
#define HEADDIM 64
#define D_INNER 512
#define NHEADS 8
#define D_XBC 640
#define NPROJ 1160
#define ZXW 1152   /* bf16 zxbc row width (z + xBC) */
#define BATCH 64
#define SEQ 250
#define ROWS (BATCH * SEQ) /* 16000 */
#define KIN 240
#define KPAD 256
#define NPAD 1280  /* padded to 10x128 col-panels for the 128x128-tile gemm1 */
#define TPAD 256   /* t padded to 256 in xcT */

typedef __bf16 bf16x8 __attribute__((ext_vector_type(8)));
typedef float f32x4 __attribute__((ext_vector_type(4)));

typedef __attribute__((address_space(1))) const void gv_t;
typedef __attribute__((address_space(3))) void lv_t;

__device__ __forceinline__ float readlane_f(float v, int lane) {
    return __uint_as_float(__builtin_amdgcn_readlane(__float_as_uint(v), lane));
}
__device__ __forceinline__ float silu_f(float x) { return x * (1.f / (1.f + __expf(-x))); }
__device__ __forceinline__ unsigned short bf16_rne(float f) {
    unsigned int u = __float_as_uint(f);
    u += 0x7fff + ((u >> 16) & 1);
    return (unsigned short)(u >> 16);
}
__device__ __forceinline__ float bf2f(unsigned short u) {
    return __uint_as_float(((unsigned int)u) << 16);
}
__device__ __forceinline__ unsigned int pack2(float a, float b) {
    return (unsigned int)bf16_rne(a) | ((unsigned int)bf16_rne(b) << 16);
}

// ---------------------------------------------------------------------------
// Kernel 0: cast_all — x -> a_bf [16000][256], W_in -> bt_bf [1280][256] (T),
// W_out -> wt_bf [256][512] (T). One launch for all three.
// ---------------------------------------------------------------------------
#define NA (ROWS * KPAD)
#define NB (NPAD * KPAD)
#define NW (D_MODEL * D_INNER)
__global__ __launch_bounds__(256) void cast_all_kernel(const float* __restrict__ x,
                                                       const float* __restrict__ Win,
                                                       const float* __restrict__ Wout,
                                                       unsigned short* __restrict__ a_bf,
                                                       unsigned short* __restrict__ bt_bf,
                                                       unsigned short* __restrict__ wt_bf) {
    int idx = blockIdx.x * 256 + threadIdx.x;
    if (idx < NA) {
        int row = idx >> 8, c = idx & 255;
        float v = (c < KIN) ? x[row * KIN + c] : 0.f;
        a_bf[idx] = bf16_rne(v);
    } else if (idx < NA + NB) {
        int r = idx - NA;
        int n = r >> 8, k = r & 255;
        float v = (n < NPROJ && k < KIN) ? Win[k * NPROJ + n] : 0.f;
        bt_bf[r] = bf16_rne(v);
    } else if (idx < NA + NB + NW) {
        int r = idx - NA - NB;
        int n = r & 255, k = r >> 8;
        wt_bf[n * D_INNER + k] = bf16_rne(Wout[k * D_MODEL + n]);
    }
}

// ---------------------------------------------------------------------------
// Kernel 1: gemm1 — m97-structure: 128x128 tile, BK=32, linear LDS,
// global_load_lds width=16 staging. Grid 10 x 125 with bijective XCD-chunk
// swizzle (m204): each XCD gets ~16 consecutive row-panels x all 10 col-blocks
// so the shared A row-panel stays in that XCD's L2. dt cols (1152..1159) get
// bias+softplus fused in the epilogue -> dtp (f32). Cols >=1160 discarded.
// ---------------------------------------------------------------------------
__global__ __launch_bounds__(256) void gemm1_mfma(const unsigned short* __restrict__ A,
                                                  const unsigned short* __restrict__ Bt,
                                                  const float* __restrict__ dt_bias,
                                                  unsigned short* __restrict__ Czx,
                                                  float* __restrict__ dtp) {
    __shared__ unsigned short As[128 * 32];
    __shared__ unsigned short Bs[128 * 32];
    const int tid = threadIdx.x;
    const int lane = tid & 63, wave = tid >> 6;
    const int wm = wave >> 1, wn = wave & 1;
    const int q = lane >> 4, l15 = lane & 15;
    // ---- bijective XCD swizzle: nwg = 1250 = 8*156 + 2 ----
    const int lin = blockIdx.y * 10 + blockIdx.x;
    const int xcd = lin & 7, rank = lin >> 3;
    const int newid = (xcd < 2 ? xcd * 157 : 2 * 157 + (xcd - 2) * 156) + rank;
    const int by = newid / 10, bx = newid - by * 10;
    const int rowBase = by * 128, colBase = bx * 128;
    f32x4 acc[4][4] = {};

    const int sr = tid >> 2;          // staging row 0..63
    const int sc = (tid & 3) * 8;     // staging col (bf16) 0,8,16,24

    const unsigned short* gA = A + (size_t)(rowBase + sr) * KPAD + sc;
    const unsigned short* gB = Bt + (size_t)(colBase + sr) * KPAD + sc;
    unsigned short* lA = &As[sr * 32 + sc];   // wave-uniform base + lane*16B
    unsigned short* lB = &Bs[sr * 32 + sc];

    for (int k0 = 0; k0 < KPAD; k0 += 32) {
        __builtin_amdgcn_global_load_lds((gv_t*)(gA + k0), (lv_t*)lA, 16, 0, 0);
        __builtin_amdgcn_global_load_lds((gv_t*)(gA + 64 * KPAD + k0),
                                         (lv_t*)(lA + 64 * 32), 16, 0, 0);
        __builtin_amdgcn_global_load_lds((gv_t*)(gB + k0), (lv_t*)lB, 16, 0, 0);
        __builtin_amdgcn_global_load_lds((gv_t*)(gB + 64 * KPAD + k0),
                                         (lv_t*)(lB + 64 * 32), 16, 0, 0);
        __syncthreads();

        bf16x8 bfr[4];
#pragma unroll
        for (int nt = 0; nt < 4; nt++)
            bfr[nt] = *(const bf16x8*)&Bs[(wn * 64 + nt * 16 + l15) * 32 + q * 8];
#pragma unroll
        for (int mt = 0; mt < 4; mt++) {
            bf16x8 afr = *(const bf16x8*)&As[(wm * 64 + mt * 16 + l15) * 32 + q * 8];
#pragma unroll
            for (int nt = 0; nt < 4; nt++)
                acc[mt][nt] = __builtin_amdgcn_mfma_f32_16x16x32_bf16(afr, bfr[nt],
                                                                      acc[mt][nt], 0, 0, 0);
        }
        __syncthreads();
    }
#pragma unroll
    for (int mt = 0; mt < 4; mt++) {
        int grow0 = rowBase + wm * 64 + mt * 16 + q * 4;
#pragma unroll
        for (int nt = 0; nt < 4; nt++) {
            int gcol = colBase + wn * 64 + nt * 16 + l15;
            if (gcol < ZXW) {
#pragma unroll
                for (int reg = 0; reg < 4; reg++) {
                    unsigned int u = bf16_rne(acc[mt][nt][reg]);
                    unsigned int partner = (unsigned int)__shfl_xor((int)u, 1, 64);
                    if ((l15 & 1) == 0)
                        *(unsigned int*)&Czx[(size_t)(grow0 + reg) * ZXW + gcol] =
                            u | (partner << 16);
                }
            } else if (gcol < NPROJ) {
                float bias = dt_bias[gcol - ZXW];
#pragma unroll
                for (int reg = 0; reg < 4; reg++) {
                    float v = acc[mt][nt][reg] + bias;
                    v = (v > 20.f) ? v : __logf(1.f + __expf(v));
                    dtp[(size_t)(grow0 + reg) * NHEADS + (gcol - ZXW)] = v;
                }
            }
        }
    }
}

// ---------------------------------------------------------------------------
// Kernel 2: conv — tiled depthwise conv4 + SiLU from bf16 zxbc (R4-proven).
// DSE: xc_bf only for B/C (cg>=8); xcT_bf only for x/B (cg<=8). dt path
// removed (fused into gemm1 epilogue); grid y = 10.
// ---------------------------------------------------------------------------
#define CT_IN_STR 68
#define CT_TR_STR 70
__global__ __launch_bounds__(256) void conv_kernel(const unsigned short* __restrict__ zxbc,
                                                   const float* __restrict__ conv_w,
                                                   const float* __restrict__ conv_b,
                                                   unsigned short* __restrict__ xc_bf,
                                                   unsigned short* __restrict__ xcT_bf) {
    const int b = blockIdx.x;
    const int t0 = blockIdx.z * 64;
    __shared__ float In[67 * CT_IN_STR];
    __shared__ unsigned short OutT[64 * CT_TR_STR];
    const int cg = blockIdx.y;
    const int tid = threadIdx.x;
    const int lane = tid & 63;
    const int w = tid >> 6;
    const int ch = cg * 64 + lane;

    for (int r = w; r < 67; r += 4) {
        int t = t0 - 3 + r;
        float v = (t >= 0 && t < SEQ)
                      ? bf2f(zxbc[(size_t)(b * SEQ + t) * ZXW + D_INNER + ch])
                      : 0.f;
        In[r * CT_IN_STR + lane] = v;
    }
    __syncthreads();
    const float w0 = conv_w[ch * 4 + 0], w1 = conv_w[ch * 4 + 1];
    const float w2 = conv_w[ch * 4 + 2], w3 = conv_w[ch * 4 + 3];
    const float bias = conv_b[ch];
    unsigned short vals[16];
#pragma unroll
    for (int i = 0; i < 16; i++) {
        int tt = w * 16 + i;
        float acc = fmaf(w3, In[(tt + 3) * CT_IN_STR + lane],
                    fmaf(w2, In[(tt + 2) * CT_IN_STR + lane],
                    fmaf(w1, In[(tt + 1) * CT_IN_STR + lane],
                    fmaf(w0, In[tt * CT_IN_STR + lane], bias))));
        float sv = silu_f(acc);
        unsigned short bv = (t0 + tt < SEQ) ? bf16_rne(sv) : (unsigned short)0;
        vals[i] = bv;
        OutT[lane * CT_TR_STR + tt] = bv;
    }
    if (cg >= 8) {  // only B (cg==8) and C (cg==9) are read from xc_bf
#pragma unroll
        for (int i = 0; i < 16; i++) {
            int tt = w * 16 + i;
            if (t0 + tt < SEQ)
                xc_bf[(size_t)(b * SEQ + t0 + tt) * D_XBC + ch] = vals[i];
        }
    }
    if (cg <= 8) {  // only x (cg<8) and B (cg==8) are read from xcT_bf
        __syncthreads();
        unsigned short* dstbase = xcT_bf + ((size_t)b * D_XBC + cg * 64) * TPAD + t0;
#pragma unroll
        for (int i = 0; i < 16; i++) {
            int c2 = w * 16 + i;
            dstbase[(size_t)c2 * TPAD + lane] = OutT[c2 * CT_TR_STR + lane];
        }
    }
}

// ---------------------------------------------------------------------------
// Kernel 3: scan_fused — R4-proven: one block per (b,h); 4 chunks sequential,
// inter-chunk state h in f32 registers + bf16 LDS mirror. 38 KB LDS ->
// 4 blocks/CU.
// ---------------------------------------------------------------------------
#define LSTR 72
__global__ __launch_bounds__(256) void scan_fused(const unsigned short* __restrict__ xc_bf,
                                                  const unsigned short* __restrict__ xcT_bf,
                                                  const float* __restrict__ dtp,
                                                  const float* __restrict__ A_log,
                                                  const float* __restrict__ Dvec,
                                                  unsigned short* __restrict__ yout_bf) {
    __shared__ unsigned short C_l[64 * LSTR];   // C, then (post-S3) BwT
    __shared__ unsigned short BP_l[64 * LSTR];  // B, then (post-S3) P
    __shared__ unsigned short XT_l[64 * LSTR];  // x^T
    __shared__ unsigned short H_l[64 * LSTR];   // h_{c-1} bf16 [p][n]
    __shared__ float cs_s[64], dts_s[64], fws_s[64];
    __shared__ float tot_s;

    const int bh = blockIdx.x;
    const int b = bh >> 3, h = bh & 7;
    const int tid = threadIdx.x;
    const int lane = tid & 63, w = tid >> 6;
    const int q = lane >> 4, l15 = lane & 15;
    const float A = -__expf(A_log[h]);
    const float Dh = Dvec[h];
    const int r = tid >> 2, c0 = (tid & 3) * 16;

    f32x4 h_acc[4] = {};  // rows p = w*16+q*4+rr, cols n = nt*16+l15

    for (int c = 0; c < 4; ++c) {
        const int t0 = c * 64;
        if (c > 0) __syncthreads();  // S0: prev-chunk LDS reads done before overwrite

        if (t0 + r < SEQ) {
            const unsigned short* rowp = xc_bf + (size_t)(b * SEQ + t0 + r) * D_XBC;
            *(uint4*)&C_l[r * LSTR + c0] = *(const uint4*)&rowp[D_INNER + D_STATE + c0];
            *(uint4*)&C_l[r * LSTR + c0 + 8] =
                *(const uint4*)&rowp[D_INNER + D_STATE + c0 + 8];
            *(uint4*)&BP_l[r * LSTR + c0] = *(const uint4*)&rowp[D_INNER + c0];
            *(uint4*)&BP_l[r * LSTR + c0 + 8] = *(const uint4*)&rowp[D_INNER + c0 + 8];
        } else {
            uint4 z = {0, 0, 0, 0};
            *(uint4*)&C_l[r * LSTR + c0] = z;
            *(uint4*)&C_l[r * LSTR + c0 + 8] = z;
            *(uint4*)&BP_l[r * LSTR + c0] = z;
            *(uint4*)&BP_l[r * LSTR + c0 + 8] = z;
        }
        {
            const unsigned short* xrow =
                xcT_bf + ((size_t)b * D_XBC + h * HEADDIM + r) * TPAD + t0;
            *(uint4*)&XT_l[r * LSTR + c0] = *(const uint4*)&xrow[c0];
            *(uint4*)&XT_l[r * LSTR + c0 + 8] = *(const uint4*)&xrow[c0 + 8];
        }
        uint4 braw0, braw1;
        {
            const unsigned short* brow =
                xcT_bf + ((size_t)b * D_XBC + D_INNER + r) * TPAD + t0 + c0;
            braw0 = *(const uint4*)&brow[0];
            braw1 = *(const uint4*)&brow[8];
        }
        if (w == 0) {
            int t = lane;
            float dtv = (t0 + t < SEQ) ? dtp[(size_t)(b * SEQ + t0 + t) * NHEADS + h] : 0.f;
            float csv = dtv * A;
#pragma unroll
            for (int o = 1; o < 64; o <<= 1) {
                float u = __shfl_up(csv, o, 64);
                if (lane >= o) csv += u;
            }
            float tot = readlane_f(csv, 63);
            cs_s[t] = csv;
            dts_s[t] = dtv;
            fws_s[t] = dtv * __expf(tot - csv);
            if (lane == 0) tot_s = tot;
        }
        __syncthreads();  // S1

        // G = C . B^T  and  y_inter = C . h_{c-1}^T
        f32x4 g[4] = {};
        f32x4 yi[4] = {};
#pragma unroll
        for (int k0 = 0; k0 < 64; k0 += 32) {
            bf16x8 ca = *(const bf16x8*)&C_l[(w * 16 + l15) * LSTR + k0 + q * 8];
#pragma unroll
            for (int nt = 0; nt < 4; nt++) {
                bf16x8 bb = *(const bf16x8*)&BP_l[(nt * 16 + l15) * LSTR + k0 + q * 8];
                g[nt] = __builtin_amdgcn_mfma_f32_16x16x32_bf16(ca, bb, g[nt], 0, 0, 0);
            }
            if (c > 0) {
#pragma unroll
                for (int nt = 0; nt < 4; nt++) {
                    bf16x8 hb = *(const bf16x8*)&H_l[(nt * 16 + l15) * LSTR + k0 + q * 8];
                    yi[nt] = __builtin_amdgcn_mfma_f32_16x16x32_bf16(ca, hb, yi[nt], 0, 0, 0);
                }
            }
        }
        __syncthreads();  // S3

        {   // C_l <- Bw (B^T row-scaled by fws)
            unsigned short tmp[16];
            const unsigned short* rp = (const unsigned short*)&braw0;
#pragma unroll
            for (int j = 0; j < 8; j++) tmp[j] = bf16_rne(bf2f(rp[j]) * fws_s[c0 + j]);
            rp = (const unsigned short*)&braw1;
#pragma unroll
            for (int j = 0; j < 8; j++) tmp[8 + j] = bf16_rne(bf2f(rp[j]) * fws_s[c0 + 8 + j]);
            *(uint4*)&C_l[r * LSTR + c0] = *(uint4*)&tmp[0];
            *(uint4*)&C_l[r * LSTR + c0 + 8] = *(uint4*)&tmp[8];
        }
#pragma unroll
        for (int nt = 0; nt < 4; nt++) {   // BP_l <- P
#pragma unroll
            for (int rr = 0; rr < 4; rr++) {
                int t = w * 16 + q * 4 + rr;
                int s = nt * 16 + l15;
                float pv = 0.f;
                if (s <= t) {
                    pv = g[nt][rr] * __expf(cs_s[t] - cs_s[s]) * dts_s[s];
                    if (s == t) pv += Dh;
                }
                unsigned int u = bf16_rne(pv);
                unsigned int partner = (unsigned int)__shfl_xor((int)u, 1, 64);
                if ((l15 & 1) == 0)
                    *(unsigned int*)&BP_l[t * LSTR + nt * 16 + l15] = u | (partner << 16);
            }
        }
        __syncthreads();  // S4

        // y_intra = P . x^T
        f32x4 y[4] = {};
#pragma unroll
        for (int k0 = 0; k0 < 64; k0 += 32) {
            bf16x8 pa = *(const bf16x8*)&BP_l[(w * 16 + l15) * LSTR + k0 + q * 8];
#pragma unroll
            for (int nt = 0; nt < 4; nt++) {
                bf16x8 xb = *(const bf16x8*)&XT_l[(nt * 16 + l15) * LSTR + k0 + q * 8];
                y[nt] = __builtin_amdgcn_mfma_f32_16x16x32_bf16(pa, xb, y[nt], 0, 0, 0);
            }
        }
        if (c < 3) {
            f32x4 st[4] = {};
#pragma unroll
            for (int k0 = 0; k0 < 64; k0 += 32) {
                bf16x8 xa = *(const bf16x8*)&XT_l[(w * 16 + l15) * LSTR + k0 + q * 8];
#pragma unroll
                for (int nt = 0; nt < 4; nt++) {
                    bf16x8 bwb = *(const bf16x8*)&C_l[(nt * 16 + l15) * LSTR + k0 + q * 8];
                    st[nt] = __builtin_amdgcn_mfma_f32_16x16x32_bf16(xa, bwb, st[nt], 0, 0, 0);
                }
            }
            const float decay = __expf(tot_s);
#pragma unroll
            for (int nt = 0; nt < 4; nt++) {
                h_acc[nt] = st[nt] + decay * h_acc[nt];
#pragma unroll
                for (int rr = 0; rr < 4; rr++) {
                    unsigned int u = bf16_rne(h_acc[nt][rr]);
                    unsigned int partner = (unsigned int)__shfl_xor((int)u, 1, 64);
                    if ((l15 & 1) == 0)
                        *(unsigned int*)&H_l[(w * 16 + q * 4 + rr) * LSTR + nt * 16 + l15] =
                            u | (partner << 16);
                }
            }
        }
        // yout = y_intra + exp(cs_t) * y_inter  (single write, no RMW)
#pragma unroll
        for (int nt = 0; nt < 4; nt++)
#pragma unroll
            for (int rr = 0; rr < 4; rr++) {
                int t = w * 16 + q * 4 + rr;
                if (t0 + t < SEQ) {
                    int p = nt * 16 + l15;
                    float yv = y[nt][rr];
                    if (c > 0) yv += __expf(cs_s[t]) * yi[nt][rr];
                    unsigned int u = bf16_rne(yv);
                    unsigned int partner = (unsigned int)__shfl_xor((int)u, 1, 64);
                    if ((l15 & 1) == 0)
                        *(unsigned int*)&yout_bf[(size_t)(b * SEQ + t0 + t) * D_INNER +
                                                 h * HEADDIM + p] = u | (partner << 16);
                }
            }
    }
}

// ---------------------------------------------------------------------------
// Kernel 4: gemm2_fused — out = selu( rms_r * ((y*silu(z)*norm_w) @ W^T) ).
// R2-proven 32-row/500-block version (grid must stay >= 2x CU count).
// ---------------------------------------------------------------------------
#define SA 40
__global__ __launch_bounds__(256) void gemm2_fused(const unsigned short* __restrict__ yout_bf,
                                                   const unsigned short* __restrict__ zxbc,
                                                   const unsigned short* __restrict__ Bt,
                                                   const float* __restrict__ norm_w,
                                                   float* __restrict__ out) {
    __shared__ unsigned short As2[32 * SA];
    __shared__ unsigned short Bs2[256 * SA];
    __shared__ float rms_s[32];
    const int tid = threadIdx.x;
    const int lane = tid & 63;
    const int wn = tid >> 6;               // wave -> 64-col slice
    const int q = lane >> 4, l15 = lane & 15;
    const int rowBase = blockIdx.x * 32;
    f32x4 acc[2][4] = {};

    const int tr = tid >> 3;               // staging row 0..31
    const int tk = (tid & 7) * 4;          // staging k-offset 0..28

    const unsigned short* yrow = yout_bf + (size_t)(rowBase + tr) * D_INNER + tk;
    const unsigned short* zrow = zxbc + (size_t)(rowBase + tr) * ZXW + tk;
    float ssq = 0.f;

    for (int k0 = 0; k0 < D_INNER; k0 += 32) {
        // ---- A: u = y*silu(z)*norm_w, accumulate g^2 ----
        uint2 yp = *(const uint2*)&yrow[k0];
        uint2 zp = *(const uint2*)&zrow[k0];
        float4 nw = *(const float4*)&norm_w[k0 + tk];
        const unsigned short* ys = (const unsigned short*)&yp;
        const unsigned short* zs = (const unsigned short*)&zp;
        float g0 = bf2f(ys[0]) * silu_f(bf2f(zs[0]));
        float g1 = bf2f(ys[1]) * silu_f(bf2f(zs[1]));
        float g2 = bf2f(ys[2]) * silu_f(bf2f(zs[2]));
        float g3 = bf2f(ys[3]) * silu_f(bf2f(zs[3]));
        ssq = fmaf(g0, g0, ssq);
        ssq = fmaf(g1, g1, ssq);
        ssq = fmaf(g2, g2, ssq);
        ssq = fmaf(g3, g3, ssq);
        uint2 pk;
        pk.x = pack2(g0 * nw.x, g1 * nw.y);
        pk.y = pack2(g2 * nw.z, g3 * nw.w);
        *(uint2*)&As2[tr * SA + tk] = pk;
        // ---- B: col `tid`, 32 k-shorts ----
        const unsigned short* brow = Bt + (size_t)tid * D_INNER + k0;
        *(uint4*)&Bs2[tid * SA + 0] = *(const uint4*)&brow[0];
        *(uint4*)&Bs2[tid * SA + 8] = *(const uint4*)&brow[8];
        *(uint4*)&Bs2[tid * SA + 16] = *(const uint4*)&brow[16];
        *(uint4*)&Bs2[tid * SA + 24] = *(const uint4*)&brow[24];
        __syncthreads();

        bf16x8 bfr[4];
#pragma unroll
        for (int nt = 0; nt < 4; nt++)
            bfr[nt] = *(const bf16x8*)&Bs2[(wn * 64 + nt * 16 + l15) * SA + q * 8];
#pragma unroll
        for (int mt = 0; mt < 2; mt++) {
            bf16x8 afr = *(const bf16x8*)&As2[(mt * 16 + l15) * SA + q * 8];
#pragma unroll
            for (int nt = 0; nt < 4; nt++)
                acc[mt][nt] = __builtin_amdgcn_mfma_f32_16x16x32_bf16(afr, bfr[nt],
                                                                      acc[mt][nt], 0, 0, 0);
        }
        __syncthreads();
    }
    // per-row rms: reduce ssq over the 8 lanes (tid&7) that share row tr
    ssq += __shfl_xor(ssq, 1, 64);
    ssq += __shfl_xor(ssq, 2, 64);
    ssq += __shfl_xor(ssq, 4, 64);
    if ((tid & 7) == 0) rms_s[tr] = rsqrtf(ssq * (1.f / 512.f) + 1e-5f);
    __syncthreads();

    const float SC = 1.0507009873554805f, AL = 1.6732632423543772f;
#pragma unroll
    for (int mt = 0; mt < 2; mt++) {
        int lrow0 = mt * 16 + q * 4;
#pragma unroll
        for (int nt = 0; nt < 4; nt++) {
            int gcol = wn * 64 + nt * 16 + l15;
            if (gcol < 240) {
#pragma unroll
                for (int reg = 0; reg < 4; reg++) {
                    float v = acc[mt][nt][reg] * rms_s[lrow0 + reg];
                    v = (v > 0.f) ? SC * v : SC * AL * (__expf(v) - 1.f);
                    out[(size_t)(rowBase + lrow0 + reg) * 240 + gcol] = v;
                }
            }
        }
    }
}

// ---------------------------------------------------------------------------
extern "C" void kernel_launch(void* const* d_in, const int* in_sizes, int n_in,
                              void* d_out, int out_size, void* d_ws, size_t ws_size,
                              hipStream_t stream) {
    const float* x = (const float*)d_in[0];
    const float* W_in = (const float*)d_in[1];
    const float* conv_w = (const float*)d_in[2];
    const float* conv_b = (const float*)d_in[3];
    const float* A_log = (const float*)d_in[4];
    const float* dt_bias = (const float*)d_in[5];
    const float* Dv = (const float*)d_in[6];
    const float* norm_w = (const float*)d_in[7];
    const float* W_out = (const float*)d_in[8];
    float* out = (float*)d_out;

    unsigned short* us = (unsigned short*)d_ws;
    unsigned short* zxbc_bf = us;                              // 16000*1152
    unsigned short* xc_bf = zxbc_bf + (size_t)ROWS * ZXW;      // 16000*640
    unsigned short* xcT_bf = xc_bf + (size_t)ROWS * D_XBC;     // 64*640*256
    unsigned short* yout_bf = xcT_bf + (size_t)BATCH * D_XBC * TPAD;  // 16000*512
    unsigned short* bt_bf = yout_bf + (size_t)ROWS * D_INNER;  // 1280*256
    unsigned short* wt_bf = bt_bf + (size_t)NPAD * KPAD;       // 256*512
    float* dtp = (float*)(wt_bf + (size_t)D_MODEL * D_INNER);  // 16000*8 f32
    unsigned short* a_bf = (unsigned short*)(dtp + (size_t)ROWS * NHEADS);  // 16000*256

    int cast_total = NA + NB + NW;
    cast_all_kernel<<<dim3((cast_total + 255) / 256), 256, 0, stream>>>(x, W_in, W_out,
                                                                        a_bf, bt_bf, wt_bf);

    gemm1_mfma<<<dim3(NPAD / 128, ROWS / 128), 256, 0, stream>>>(a_bf, bt_bf, dt_bias,
                                                                 zxbc_bf, dtp);

    conv_kernel<<<dim3(BATCH, 10, 4), 256, 0, stream>>>(zxbc_bf, conv_w, conv_b,
                                                        xc_bf, xcT_bf);

    scan_fused<<<dim3(BATCH * NHEADS), 256, 0, stream>>>(xc_bf, xcT_bf, dtp, A_log, Dv,
                                                         yout_bf);

    gemm2_fused<<<dim3(ROWS / 32), 256, 0, stream>>>(yout_bf, zxbc_bf, wt_bf, norm_w, out);
}

// Round 8
// 189.528 us; speedup vs baseline: 1.0611x; 1.0149x over previous
//
#include <hip/hip_runtime.h>
#include <cstdint>
#include <cstddef>

#define D_MODEL 256
#define D_STATE 64
#define HEADDIM 64
#define D_INNER 512
#define NHEADS 8
#define D_XBC 640
#define NPROJ 1160
#define ZXW 1152   /* bf16 zxbc row width (z + xBC) */
#define BATCH 64
#define SEQ 250
#define ROWS (BATCH * SEQ) /* 16000 */
#define KIN 240
#define KPAD 256
#define NPAD 1280  /* padded to 10x128 col-panels for the 128x128-tile gemm1 */
#define TPAD 256   /* t padded to 256 in xcT */

typedef __bf16 bf16x8 __attribute__((ext_vector_type(8)));
typedef float f32x4 __attribute__((ext_vector_type(4)));

typedef __attribute__((address_space(1))) const void gv_t;
typedef __attribute__((address_space(3))) void lv_t;

__device__ __forceinline__ float readlane_f(float v, int lane) {
    return __uint_as_float(__builtin_amdgcn_readlane(__float_as_uint(v), lane));
}
__device__ __forceinline__ float silu_f(float x) { return x * (1.f / (1.f + __expf(-x))); }
__device__ __forceinline__ unsigned short bf16_rne(float f) {
    unsigned int u = __float_as_uint(f);
    u += 0x7fff + ((u >> 16) & 1);
    return (unsigned short)(u >> 16);
}
__device__ __forceinline__ float bf2f(unsigned short u) {
    return __uint_as_float(((unsigned int)u) << 16);
}
__device__ __forceinline__ unsigned int pack2(float a, float b) {
    return (unsigned int)bf16_rne(a) | ((unsigned int)bf16_rne(b) << 16);
}

// ---------------------------------------------------------------------------
// Kernel 0: cast_all — x -> a_bf [16000][256], W_in -> bt_bf [1280][256] (T),
// W_out -> wt_bf [256][512] (T). One launch for all three.
// ---------------------------------------------------------------------------
#define NA (ROWS * KPAD)
#define NB (NPAD * KPAD)
#define NW (D_MODEL * D_INNER)
__global__ __launch_bounds__(256) void cast_all_kernel(const float* __restrict__ x,
                                                       const float* __restrict__ Win,
                                                       const float* __restrict__ Wout,
                                                       unsigned short* __restrict__ a_bf,
                                                       unsigned short* __restrict__ bt_bf,
                                                       unsigned short* __restrict__ wt_bf) {
    int idx = blockIdx.x * 256 + threadIdx.x;
    if (idx < NA) {
        int row = idx >> 8, c = idx & 255;
        float v = (c < KIN) ? x[row * KIN + c] : 0.f;
        a_bf[idx] = bf16_rne(v);
    } else if (idx < NA + NB) {
        int r = idx - NA;
        int n = r >> 8, k = r & 255;
        float v = (n < NPROJ && k < KIN) ? Win[k * NPROJ + n] : 0.f;
        bt_bf[r] = bf16_rne(v);
    } else if (idx < NA + NB + NW) {
        int r = idx - NA - NB;
        int n = r & 255, k = r >> 8;
        wt_bf[n * D_INNER + k] = bf16_rne(Wout[k * D_MODEL + n]);
    }
}

// ---------------------------------------------------------------------------
// Kernel 1: gemm1 — m97-structure: 128x128 tile, BK=32, linear LDS,
// global_load_lds width=16 staging. Grid 10 x 125 with bijective XCD-chunk
// swizzle (m204). dt cols (1152..1159) get bias+softplus fused in the
// epilogue -> dtp (f32). Cols >=1160 discarded.
// ---------------------------------------------------------------------------
__global__ __launch_bounds__(256) void gemm1_mfma(const unsigned short* __restrict__ A,
                                                  const unsigned short* __restrict__ Bt,
                                                  const float* __restrict__ dt_bias,
                                                  unsigned short* __restrict__ Czx,
                                                  float* __restrict__ dtp) {
    __shared__ unsigned short As[128 * 32];
    __shared__ unsigned short Bs[128 * 32];
    const int tid = threadIdx.x;
    const int lane = tid & 63, wave = tid >> 6;
    const int wm = wave >> 1, wn = wave & 1;
    const int q = lane >> 4, l15 = lane & 15;
    // ---- bijective XCD swizzle: nwg = 1250 = 8*156 + 2 ----
    const int lin = blockIdx.y * 10 + blockIdx.x;
    const int xcd = lin & 7, rank = lin >> 3;
    const int newid = (xcd < 2 ? xcd * 157 : 2 * 157 + (xcd - 2) * 156) + rank;
    const int by = newid / 10, bx = newid - by * 10;
    const int rowBase = by * 128, colBase = bx * 128;
    f32x4 acc[4][4] = {};

    const int sr = tid >> 2;          // staging row 0..63
    const int sc = (tid & 3) * 8;     // staging col (bf16) 0,8,16,24

    const unsigned short* gA = A + (size_t)(rowBase + sr) * KPAD + sc;
    const unsigned short* gB = Bt + (size_t)(colBase + sr) * KPAD + sc;
    unsigned short* lA = &As[sr * 32 + sc];   // wave-uniform base + lane*16B
    unsigned short* lB = &Bs[sr * 32 + sc];

    for (int k0 = 0; k0 < KPAD; k0 += 32) {
        __builtin_amdgcn_global_load_lds((gv_t*)(gA + k0), (lv_t*)lA, 16, 0, 0);
        __builtin_amdgcn_global_load_lds((gv_t*)(gA + 64 * KPAD + k0),
                                         (lv_t*)(lA + 64 * 32), 16, 0, 0);
        __builtin_amdgcn_global_load_lds((gv_t*)(gB + k0), (lv_t*)lB, 16, 0, 0);
        __builtin_amdgcn_global_load_lds((gv_t*)(gB + 64 * KPAD + k0),
                                         (lv_t*)(lB + 64 * 32), 16, 0, 0);
        __syncthreads();

        bf16x8 bfr[4];
#pragma unroll
        for (int nt = 0; nt < 4; nt++)
            bfr[nt] = *(const bf16x8*)&Bs[(wn * 64 + nt * 16 + l15) * 32 + q * 8];
#pragma unroll
        for (int mt = 0; mt < 4; mt++) {
            bf16x8 afr = *(const bf16x8*)&As[(wm * 64 + mt * 16 + l15) * 32 + q * 8];
#pragma unroll
            for (int nt = 0; nt < 4; nt++)
                acc[mt][nt] = __builtin_amdgcn_mfma_f32_16x16x32_bf16(afr, bfr[nt],
                                                                      acc[mt][nt], 0, 0, 0);
        }
        __syncthreads();
    }
#pragma unroll
    for (int mt = 0; mt < 4; mt++) {
        int grow0 = rowBase + wm * 64 + mt * 16 + q * 4;
#pragma unroll
        for (int nt = 0; nt < 4; nt++) {
            int gcol = colBase + wn * 64 + nt * 16 + l15;
            if (gcol < ZXW) {
#pragma unroll
                for (int reg = 0; reg < 4; reg++) {
                    unsigned int u = bf16_rne(acc[mt][nt][reg]);
                    unsigned int partner = (unsigned int)__shfl_xor((int)u, 1, 64);
                    if ((l15 & 1) == 0)
                        *(unsigned int*)&Czx[(size_t)(grow0 + reg) * ZXW + gcol] =
                            u | (partner << 16);
                }
            } else if (gcol < NPROJ) {
                float bias = dt_bias[gcol - ZXW];
#pragma unroll
                for (int reg = 0; reg < 4; reg++) {
                    float v = acc[mt][nt][reg] + bias;
                    v = (v > 20.f) ? v : __logf(1.f + __expf(v));
                    dtp[(size_t)(grow0 + reg) * NHEADS + (gcol - ZXW)] = v;
                }
            }
        }
    }
}

// ---------------------------------------------------------------------------
// Kernel 2: conv — tiled depthwise conv4 + SiLU from bf16 zxbc (R4-proven).
// DSE: xc_bf only for B/C (cg>=8); xcT_bf only for x/B (cg<=8).
// ---------------------------------------------------------------------------
#define CT_IN_STR 68
#define CT_TR_STR 70
__global__ __launch_bounds__(256) void conv_kernel(const unsigned short* __restrict__ zxbc,
                                                   const float* __restrict__ conv_w,
                                                   const float* __restrict__ conv_b,
                                                   unsigned short* __restrict__ xc_bf,
                                                   unsigned short* __restrict__ xcT_bf) {
    const int b = blockIdx.x;
    const int t0 = blockIdx.z * 64;
    __shared__ float In[67 * CT_IN_STR];
    __shared__ unsigned short OutT[64 * CT_TR_STR];
    const int cg = blockIdx.y;
    const int tid = threadIdx.x;
    const int lane = tid & 63;
    const int w = tid >> 6;
    const int ch = cg * 64 + lane;

    for (int r = w; r < 67; r += 4) {
        int t = t0 - 3 + r;
        float v = (t >= 0 && t < SEQ)
                      ? bf2f(zxbc[(size_t)(b * SEQ + t) * ZXW + D_INNER + ch])
                      : 0.f;
        In[r * CT_IN_STR + lane] = v;
    }
    __syncthreads();
    const float w0 = conv_w[ch * 4 + 0], w1 = conv_w[ch * 4 + 1];
    const float w2 = conv_w[ch * 4 + 2], w3 = conv_w[ch * 4 + 3];
    const float bias = conv_b[ch];
    unsigned short vals[16];
#pragma unroll
    for (int i = 0; i < 16; i++) {
        int tt = w * 16 + i;
        float acc = fmaf(w3, In[(tt + 3) * CT_IN_STR + lane],
                    fmaf(w2, In[(tt + 2) * CT_IN_STR + lane],
                    fmaf(w1, In[(tt + 1) * CT_IN_STR + lane],
                    fmaf(w0, In[tt * CT_IN_STR + lane], bias))));
        float sv = silu_f(acc);
        unsigned short bv = (t0 + tt < SEQ) ? bf16_rne(sv) : (unsigned short)0;
        vals[i] = bv;
        OutT[lane * CT_TR_STR + tt] = bv;
    }
    if (cg >= 8) {  // only B (cg==8) and C (cg==9) are read from xc_bf
#pragma unroll
        for (int i = 0; i < 16; i++) {
            int tt = w * 16 + i;
            if (t0 + tt < SEQ)
                xc_bf[(size_t)(b * SEQ + t0 + tt) * D_XBC + ch] = vals[i];
        }
    }
    if (cg <= 8) {  // only x (cg<8) and B (cg==8) are read from xcT_bf
        __syncthreads();
        unsigned short* dstbase = xcT_bf + ((size_t)b * D_XBC + cg * 64) * TPAD + t0;
#pragma unroll
        for (int i = 0; i < 16; i++) {
            int c2 = w * 16 + i;
            dstbase[(size_t)c2 * TPAD + lane] = OutT[c2 * CT_TR_STR + lane];
        }
    }
}

// ---------------------------------------------------------------------------
// Kernel 3: scan_fused v3 — R4 structure + T14 async-stage prefetch:
// chunk c+1's global data is loaded into registers right after S1 of chunk c
// (latency hides under G-MFMA/S3/P/S4/y-MFMA), replayed regs->LDS at chunk
// top. dtp for all 4 chunks prefetched once in the prologue. All 512 blocks
// co-resident (2/CU) -> duration == one block's serial wall time; this cuts
// 3x global-load latency off that path. Math order identical to R7.
// ---------------------------------------------------------------------------
#define LSTR 72
__global__ __launch_bounds__(256) void scan_fused(const unsigned short* __restrict__ xc_bf,
                                                  const unsigned short* __restrict__ xcT_bf,
                                                  const float* __restrict__ dtp,
                                                  const float* __restrict__ A_log,
                                                  const float* __restrict__ Dvec,
                                                  unsigned short* __restrict__ yout_bf) {
    __shared__ unsigned short C_l[64 * LSTR];   // C, then (post-S3) BwT
    __shared__ unsigned short BP_l[64 * LSTR];  // B, then (post-S3) P
    __shared__ unsigned short XT_l[64 * LSTR];  // x^T
    __shared__ unsigned short H_l[64 * LSTR];   // h_{c-1} bf16 [p][n]
    __shared__ float cs_s[64], dts_s[64], fws_s[64];
    __shared__ float tot_s;

    const int bh = blockIdx.x;
    const int b = bh >> 3, h = bh & 7;
    const int tid = threadIdx.x;
    const int lane = tid & 63, w = tid >> 6;
    const int q = lane >> 4, l15 = lane & 15;
    const float A = -__expf(A_log[h]);
    const float Dh = Dvec[h];
    const int r = tid >> 2, c0 = (tid & 3) * 16;

    f32x4 h_acc[4] = {};  // rows p = w*16+q*4+rr, cols n = nt*16+l15

    // ---- prologue: dtp for all 4 chunks (w==0 lanes), named scalars ----
    float pdt0 = 0.f, pdt1 = 0.f, pdt2 = 0.f, pdt3 = 0.f;
    if (w == 0) {
        const float* dp = dtp + (size_t)(b * SEQ) * NHEADS + h;
        pdt0 = dp[(0 * 64 + lane) * NHEADS];
        pdt1 = dp[(1 * 64 + lane) * NHEADS];
        pdt2 = dp[(2 * 64 + lane) * NHEADS];
        if (192 + lane < SEQ) pdt3 = dp[(192 + lane) * NHEADS];
    }

    // ---- prologue: prefetch chunk 0 into registers ----
    uint4 pC0, pC1, pB0, pB1, pX0, pX1, pbr0, pbr1;
    {
        const unsigned short* rowp = xc_bf + (size_t)(b * SEQ + r) * D_XBC;
        pC0 = *(const uint4*)&rowp[D_INNER + D_STATE + c0];
        pC1 = *(const uint4*)&rowp[D_INNER + D_STATE + c0 + 8];
        pB0 = *(const uint4*)&rowp[D_INNER + c0];
        pB1 = *(const uint4*)&rowp[D_INNER + c0 + 8];
        const unsigned short* xrow = xcT_bf + ((size_t)b * D_XBC + h * HEADDIM + r) * TPAD;
        pX0 = *(const uint4*)&xrow[c0];
        pX1 = *(const uint4*)&xrow[c0 + 8];
        const unsigned short* brow = xcT_bf + ((size_t)b * D_XBC + D_INNER + r) * TPAD + c0;
        pbr0 = *(const uint4*)&brow[0];
        pbr1 = *(const uint4*)&brow[8];
    }

    for (int c = 0; c < 4; ++c) {
        const int t0 = c * 64;
        if (c > 0) __syncthreads();  // S0: prev-chunk LDS reads done before overwrite

        // ---- replay prefetched regs -> LDS ----
        *(uint4*)&C_l[r * LSTR + c0] = pC0;
        *(uint4*)&C_l[r * LSTR + c0 + 8] = pC1;
        *(uint4*)&BP_l[r * LSTR + c0] = pB0;
        *(uint4*)&BP_l[r * LSTR + c0 + 8] = pB1;
        *(uint4*)&XT_l[r * LSTR + c0] = pX0;
        *(uint4*)&XT_l[r * LSTR + c0 + 8] = pX1;
        const uint4 braw0 = pbr0, braw1 = pbr1;  // keep for post-S3 Bw phase

        if (w == 0) {
            int t = lane;
            float dtv = (c == 0) ? pdt0 : (c == 1) ? pdt1 : (c == 2) ? pdt2 : pdt3;
            float csv = dtv * A;
#pragma unroll
            for (int o = 1; o < 64; o <<= 1) {
                float u = __shfl_up(csv, o, 64);
                if (lane >= o) csv += u;
            }
            float tot = readlane_f(csv, 63);
            cs_s[t] = csv;
            dts_s[t] = dtv;
            fws_s[t] = dtv * __expf(tot - csv);
            if (lane == 0) tot_s = tot;
        }
        __syncthreads();  // S1

        // ---- issue chunk c+1 prefetch (lands under the compute below) ----
        if (c < 3) {
            const int t1 = t0 + 64;
            if (t1 + r < SEQ) {
                const unsigned short* rowp = xc_bf + (size_t)(b * SEQ + t1 + r) * D_XBC;
                pC0 = *(const uint4*)&rowp[D_INNER + D_STATE + c0];
                pC1 = *(const uint4*)&rowp[D_INNER + D_STATE + c0 + 8];
                pB0 = *(const uint4*)&rowp[D_INNER + c0];
                pB1 = *(const uint4*)&rowp[D_INNER + c0 + 8];
            } else {
                uint4 z = {0, 0, 0, 0};
                pC0 = z; pC1 = z; pB0 = z; pB1 = z;
            }
            const unsigned short* xrow =
                xcT_bf + ((size_t)b * D_XBC + h * HEADDIM + r) * TPAD + t1;
            pX0 = *(const uint4*)&xrow[c0];
            pX1 = *(const uint4*)&xrow[c0 + 8];
            const unsigned short* brow =
                xcT_bf + ((size_t)b * D_XBC + D_INNER + r) * TPAD + t1 + c0;
            pbr0 = *(const uint4*)&brow[0];
            pbr1 = *(const uint4*)&brow[8];
        }

        // G = C . B^T  and  y_inter = C . h_{c-1}^T
        f32x4 g[4] = {};
        f32x4 yi[4] = {};
#pragma unroll
        for (int k0 = 0; k0 < 64; k0 += 32) {
            bf16x8 ca = *(const bf16x8*)&C_l[(w * 16 + l15) * LSTR + k0 + q * 8];
#pragma unroll
            for (int nt = 0; nt < 4; nt++) {
                bf16x8 bb = *(const bf16x8*)&BP_l[(nt * 16 + l15) * LSTR + k0 + q * 8];
                g[nt] = __builtin_amdgcn_mfma_f32_16x16x32_bf16(ca, bb, g[nt], 0, 0, 0);
            }
            if (c > 0) {
#pragma unroll
                for (int nt = 0; nt < 4; nt++) {
                    bf16x8 hb = *(const bf16x8*)&H_l[(nt * 16 + l15) * LSTR + k0 + q * 8];
                    yi[nt] = __builtin_amdgcn_mfma_f32_16x16x32_bf16(ca, hb, yi[nt], 0, 0, 0);
                }
            }
        }
        __syncthreads();  // S3

        {   // C_l <- Bw (B^T row-scaled by fws)
            unsigned short tmp[16];
            const unsigned short* rp = (const unsigned short*)&braw0;
#pragma unroll
            for (int j = 0; j < 8; j++) tmp[j] = bf16_rne(bf2f(rp[j]) * fws_s[c0 + j]);
            rp = (const unsigned short*)&braw1;
#pragma unroll
            for (int j = 0; j < 8; j++) tmp[8 + j] = bf16_rne(bf2f(rp[j]) * fws_s[c0 + 8 + j]);
            *(uint4*)&C_l[r * LSTR + c0] = *(uint4*)&tmp[0];
            *(uint4*)&C_l[r * LSTR + c0 + 8] = *(uint4*)&tmp[8];
        }
#pragma unroll
        for (int nt = 0; nt < 4; nt++) {   // BP_l <- P
#pragma unroll
            for (int rr = 0; rr < 4; rr++) {
                int t = w * 16 + q * 4 + rr;
                int s = nt * 16 + l15;
                float pv = 0.f;
                if (s <= t) {
                    pv = g[nt][rr] * __expf(cs_s[t] - cs_s[s]) * dts_s[s];
                    if (s == t) pv += Dh;
                }
                unsigned int u = bf16_rne(pv);
                unsigned int partner = (unsigned int)__shfl_xor((int)u, 1, 64);
                if ((l15 & 1) == 0)
                    *(unsigned int*)&BP_l[t * LSTR + nt * 16 + l15] = u | (partner << 16);
            }
        }
        __syncthreads();  // S4

        // y_intra = P . x^T
        f32x4 y[4] = {};
#pragma unroll
        for (int k0 = 0; k0 < 64; k0 += 32) {
            bf16x8 pa = *(const bf16x8*)&BP_l[(w * 16 + l15) * LSTR + k0 + q * 8];
#pragma unroll
            for (int nt = 0; nt < 4; nt++) {
                bf16x8 xb = *(const bf16x8*)&XT_l[(nt * 16 + l15) * LSTR + k0 + q * 8];
                y[nt] = __builtin_amdgcn_mfma_f32_16x16x32_bf16(pa, xb, y[nt], 0, 0, 0);
            }
        }
        if (c < 3) {
            f32x4 st[4] = {};
#pragma unroll
            for (int k0 = 0; k0 < 64; k0 += 32) {
                bf16x8 xa = *(const bf16x8*)&XT_l[(w * 16 + l15) * LSTR + k0 + q * 8];
#pragma unroll
                for (int nt = 0; nt < 4; nt++) {
                    bf16x8 bwb = *(const bf16x8*)&C_l[(nt * 16 + l15) * LSTR + k0 + q * 8];
                    st[nt] = __builtin_amdgcn_mfma_f32_16x16x32_bf16(xa, bwb, st[nt], 0, 0, 0);
                }
            }
            const float decay = __expf(tot_s);
#pragma unroll
            for (int nt = 0; nt < 4; nt++) {
                h_acc[nt] = st[nt] + decay * h_acc[nt];
#pragma unroll
                for (int rr = 0; rr < 4; rr++) {
                    unsigned int u = bf16_rne(h_acc[nt][rr]);
                    unsigned int partner = (unsigned int)__shfl_xor((int)u, 1, 64);
                    if ((l15 & 1) == 0)
                        *(unsigned int*)&H_l[(w * 16 + q * 4 + rr) * LSTR + nt * 16 + l15] =
                            u | (partner << 16);
                }
            }
        }
        // yout = y_intra + exp(cs_t) * y_inter  (single write, no RMW)
#pragma unroll
        for (int nt = 0; nt < 4; nt++)
#pragma unroll
            for (int rr = 0; rr < 4; rr++) {
                int t = w * 16 + q * 4 + rr;
                if (t0 + t < SEQ) {
                    int p = nt * 16 + l15;
                    float yv = y[nt][rr];
                    if (c > 0) yv += __expf(cs_s[t]) * yi[nt][rr];
                    unsigned int u = bf16_rne(yv);
                    unsigned int partner = (unsigned int)__shfl_xor((int)u, 1, 64);
                    if ((l15 & 1) == 0)
                        *(unsigned int*)&yout_bf[(size_t)(b * SEQ + t0 + t) * D_INNER +
                                                 h * HEADDIM + p] = u | (partner << 16);
                }
            }
    }
}

// ---------------------------------------------------------------------------
// Kernel 4: gemm2_fused — out = selu( rms_r * ((y*silu(z)*norm_w) @ W^T) ).
// R2-proven 32-row/500-block version (grid must stay >= 2x CU count).
// ---------------------------------------------------------------------------
#define SA 40
__global__ __launch_bounds__(256) void gemm2_fused(const unsigned short* __restrict__ yout_bf,
                                                   const unsigned short* __restrict__ zxbc,
                                                   const unsigned short* __restrict__ Bt,
                                                   const float* __restrict__ norm_w,
                                                   float* __restrict__ out) {
    __shared__ unsigned short As2[32 * SA];
    __shared__ unsigned short Bs2[256 * SA];
    __shared__ float rms_s[32];
    const int tid = threadIdx.x;
    const int lane = tid & 63;
    const int wn = tid >> 6;               // wave -> 64-col slice
    const int q = lane >> 4, l15 = lane & 15;
    const int rowBase = blockIdx.x * 32;
    f32x4 acc[2][4] = {};

    const int tr = tid >> 3;               // staging row 0..31
    const int tk = (tid & 7) * 4;          // staging k-offset 0..28

    const unsigned short* yrow = yout_bf + (size_t)(rowBase + tr) * D_INNER + tk;
    const unsigned short* zrow = zxbc + (size_t)(rowBase + tr) * ZXW + tk;
    float ssq = 0.f;

    for (int k0 = 0; k0 < D_INNER; k0 += 32) {
        // ---- A: u = y*silu(z)*norm_w, accumulate g^2 ----
        uint2 yp = *(const uint2*)&yrow[k0];
        uint2 zp = *(const uint2*)&zrow[k0];
        float4 nw = *(const float4*)&norm_w[k0 + tk];
        const unsigned short* ys = (const unsigned short*)&yp;
        const unsigned short* zs = (const unsigned short*)&zp;
        float g0 = bf2f(ys[0]) * silu_f(bf2f(zs[0]));
        float g1 = bf2f(ys[1]) * silu_f(bf2f(zs[1]));
        float g2 = bf2f(ys[2]) * silu_f(bf2f(zs[2]));
        float g3 = bf2f(ys[3]) * silu_f(bf2f(zs[3]));
        ssq = fmaf(g0, g0, ssq);
        ssq = fmaf(g1, g1, ssq);
        ssq = fmaf(g2, g2, ssq);
        ssq = fmaf(g3, g3, ssq);
        uint2 pk;
        pk.x = pack2(g0 * nw.x, g1 * nw.y);
        pk.y = pack2(g2 * nw.z, g3 * nw.w);
        *(uint2*)&As2[tr * SA + tk] = pk;
        // ---- B: col `tid`, 32 k-shorts ----
        const unsigned short* brow = Bt + (size_t)tid * D_INNER + k0;
        *(uint4*)&Bs2[tid * SA + 0] = *(const uint4*)&brow[0];
        *(uint4*)&Bs2[tid * SA + 8] = *(const uint4*)&brow[8];
        *(uint4*)&Bs2[tid * SA + 16] = *(const uint4*)&brow[16];
        *(uint4*)&Bs2[tid * SA + 24] = *(const uint4*)&brow[24];
        __syncthreads();

        bf16x8 bfr[4];
#pragma unroll
        for (int nt = 0; nt < 4; nt++)
            bfr[nt] = *(const bf16x8*)&Bs2[(wn * 64 + nt * 16 + l15) * SA + q * 8];
#pragma unroll
        for (int mt = 0; mt < 2; mt++) {
            bf16x8 afr = *(const bf16x8*)&As2[(mt * 16 + l15) * SA + q * 8];
#pragma unroll
            for (int nt = 0; nt < 4; nt++)
                acc[mt][nt] = __builtin_amdgcn_mfma_f32_16x16x32_bf16(afr, bfr[nt],
                                                                      acc[mt][nt], 0, 0, 0);
        }
        __syncthreads();
    }
    // per-row rms: reduce ssq over the 8 lanes (tid&7) that share row tr
    ssq += __shfl_xor(ssq, 1, 64);
    ssq += __shfl_xor(ssq, 2, 64);
    ssq += __shfl_xor(ssq, 4, 64);
    if ((tid & 7) == 0) rms_s[tr] = rsqrtf(ssq * (1.f / 512.f) + 1e-5f);
    __syncthreads();

    const float SC = 1.0507009873554805f, AL = 1.6732632423543772f;
#pragma unroll
    for (int mt = 0; mt < 2; mt++) {
        int lrow0 = mt * 16 + q * 4;
#pragma unroll
        for (int nt = 0; nt < 4; nt++) {
            int gcol = wn * 64 + nt * 16 + l15;
            if (gcol < 240) {
#pragma unroll
                for (int reg = 0; reg < 4; reg++) {
                    float v = acc[mt][nt][reg] * rms_s[lrow0 + reg];
                    v = (v > 0.f) ? SC * v : SC * AL * (__expf(v) - 1.f);
                    out[(size_t)(rowBase + lrow0 + reg) * 240 + gcol] = v;
                }
            }
        }
    }
}

// ---------------------------------------------------------------------------
extern "C" void kernel_launch(void* const* d_in, const int* in_sizes, int n_in,
                              void* d_out, int out_size, void* d_ws, size_t ws_size,
                              hipStream_t stream) {
    const float* x = (const float*)d_in[0];
    const float* W_in = (const float*)d_in[1];
    const float* conv_w = (const float*)d_in[2];
    const float* conv_b = (const float*)d_in[3];
    const float* A_log = (const float*)d_in[4];
    const float* dt_bias = (const float*)d_in[5];
    const float* Dv = (const float*)d_in[6];
    const float* norm_w = (const float*)d_in[7];
    const float* W_out = (const float*)d_in[8];
    float* out = (float*)d_out;

    unsigned short* us = (unsigned short*)d_ws;
    unsigned short* zxbc_bf = us;                              // 16000*1152
    unsigned short* xc_bf = zxbc_bf + (size_t)ROWS * ZXW;      // 16000*640
    unsigned short* xcT_bf = xc_bf + (size_t)ROWS * D_XBC;     // 64*640*256
    unsigned short* yout_bf = xcT_bf + (size_t)BATCH * D_XBC * TPAD;  // 16000*512
    unsigned short* bt_bf = yout_bf + (size_t)ROWS * D_INNER;  // 1280*256
    unsigned short* wt_bf = bt_bf + (size_t)NPAD * KPAD;       // 256*512
    float* dtp = (float*)(wt_bf + (size_t)D_MODEL * D_INNER);  // 16000*8 f32
    unsigned short* a_bf = (unsigned short*)(dtp + (size_t)ROWS * NHEADS);  // 16000*256

    int cast_total = NA + NB + NW;
    cast_all_kernel<<<dim3((cast_total + 255) / 256), 256, 0, stream>>>(x, W_in, W_out,
                                                                        a_bf, bt_bf, wt_bf);

    gemm1_mfma<<<dim3(NPAD / 128, ROWS / 128), 256, 0, stream>>>(a_bf, bt_bf, dt_bias,
                                                                 zxbc_bf, dtp);

    conv_kernel<<<dim3(BATCH, 10, 4), 256, 0, stream>>>(zxbc_bf, conv_w, conv_b,
                                                        xc_bf, xcT_bf);

    scan_fused<<<dim3(BATCH * NHEADS), 256, 0, stream>>>(xc_bf, xcT_bf, dtp, A_log, Dv,
                                                         yout_bf);

    gemm2_fused<<<dim3(ROWS / 32), 256, 0, stream>>>(yout_bf, zxbc_bf, wt_bf, norm_w, out);
}

// Round 9
// 180.848 us; speedup vs baseline: 1.1120x; 1.0480x over previous
//
#include <hip/hip_runtime.h>
#include <cstdint>
#include <cstddef>

#define D_MODEL 256
#define D_STATE 64
#define HEADDIM 64
#define D_INNER 512
#define NHEADS 8
#define D_XBC 640
#define NPROJ 1160
#define ZXW 1152   /* bf16 zxbc row width (z + xBC) */
#define BATCH 64
#define SEQ 250
#define ROWS (BATCH * SEQ) /* 16000 */
#define KIN 240
#define KPAD 256
#define NPAD 1280  /* padded to 10x128 col-panels for the 128x128-tile gemm1 */
#define TPAD 256   /* t padded to 256 in xcT */

typedef __bf16 bf16x8 __attribute__((ext_vector_type(8)));
typedef float f32x4 __attribute__((ext_vector_type(4)));

typedef __attribute__((address_space(1))) const void gv_t;
typedef __attribute__((address_space(3))) void lv_t;

__device__ __forceinline__ float readlane_f(float v, int lane) {
    return __uint_as_float(__builtin_amdgcn_readlane(__float_as_uint(v), lane));
}
__device__ __forceinline__ float silu_f(float x) { return x * (1.f / (1.f + __expf(-x))); }
__device__ __forceinline__ unsigned short bf16_rne(float f) {
    unsigned int u = __float_as_uint(f);
    u += 0x7fff + ((u >> 16) & 1);
    return (unsigned short)(u >> 16);
}
__device__ __forceinline__ float bf2f(unsigned short u) {
    return __uint_as_float(((unsigned int)u) << 16);
}
__device__ __forceinline__ unsigned int pack2(float a, float b) {
    return (unsigned int)bf16_rne(a) | ((unsigned int)bf16_rne(b) << 16);
}

// ---------------------------------------------------------------------------
// Kernel 0: cast_all — x -> a_bf [16000][256], W_in -> bt_bf [1280][256] (T),
// W_out -> wt_bf [256][512] (T). One launch for all three.
// ---------------------------------------------------------------------------
#define NA (ROWS * KPAD)
#define NB (NPAD * KPAD)
#define NW (D_MODEL * D_INNER)
__global__ __launch_bounds__(256) void cast_all_kernel(const float* __restrict__ x,
                                                       const float* __restrict__ Win,
                                                       const float* __restrict__ Wout,
                                                       unsigned short* __restrict__ a_bf,
                                                       unsigned short* __restrict__ bt_bf,
                                                       unsigned short* __restrict__ wt_bf) {
    int idx = blockIdx.x * 256 + threadIdx.x;
    if (idx < NA) {
        int row = idx >> 8, c = idx & 255;
        float v = (c < KIN) ? x[row * KIN + c] : 0.f;
        a_bf[idx] = bf16_rne(v);
    } else if (idx < NA + NB) {
        int r = idx - NA;
        int n = r >> 8, k = r & 255;
        float v = (n < NPROJ && k < KIN) ? Win[k * NPROJ + n] : 0.f;
        bt_bf[r] = bf16_rne(v);
    } else if (idx < NA + NB + NW) {
        int r = idx - NA - NB;
        int n = r & 255, k = r >> 8;
        wt_bf[n * D_INNER + k] = bf16_rne(Wout[k * D_MODEL + n]);
    }
}

// ---------------------------------------------------------------------------
// Kernel 1: gemm1 — m97-structure: 128x128 tile, BK=32, linear LDS,
// global_load_lds width=16 staging. Grid 10 x 125 with bijective XCD-chunk
// swizzle (m204). dt cols (1152..1159) get bias+softplus fused in the
// epilogue -> dtp (f32). Cols >=1160 discarded.
// ---------------------------------------------------------------------------
__global__ __launch_bounds__(256) void gemm1_mfma(const unsigned short* __restrict__ A,
                                                  const unsigned short* __restrict__ Bt,
                                                  const float* __restrict__ dt_bias,
                                                  unsigned short* __restrict__ Czx,
                                                  float* __restrict__ dtp) {
    __shared__ unsigned short As[128 * 32];
    __shared__ unsigned short Bs[128 * 32];
    const int tid = threadIdx.x;
    const int lane = tid & 63, wave = tid >> 6;
    const int wm = wave >> 1, wn = wave & 1;
    const int q = lane >> 4, l15 = lane & 15;
    // ---- bijective XCD swizzle: nwg = 1250 = 8*156 + 2 ----
    const int lin = blockIdx.y * 10 + blockIdx.x;
    const int xcd = lin & 7, rank = lin >> 3;
    const int newid = (xcd < 2 ? xcd * 157 : 2 * 157 + (xcd - 2) * 156) + rank;
    const int by = newid / 10, bx = newid - by * 10;
    const int rowBase = by * 128, colBase = bx * 128;
    f32x4 acc[4][4] = {};

    const int sr = tid >> 2;          // staging row 0..63
    const int sc = (tid & 3) * 8;     // staging col (bf16) 0,8,16,24

    const unsigned short* gA = A + (size_t)(rowBase + sr) * KPAD + sc;
    const unsigned short* gB = Bt + (size_t)(colBase + sr) * KPAD + sc;
    unsigned short* lA = &As[sr * 32 + sc];   // wave-uniform base + lane*16B
    unsigned short* lB = &Bs[sr * 32 + sc];

    for (int k0 = 0; k0 < KPAD; k0 += 32) {
        __builtin_amdgcn_global_load_lds((gv_t*)(gA + k0), (lv_t*)lA, 16, 0, 0);
        __builtin_amdgcn_global_load_lds((gv_t*)(gA + 64 * KPAD + k0),
                                         (lv_t*)(lA + 64 * 32), 16, 0, 0);
        __builtin_amdgcn_global_load_lds((gv_t*)(gB + k0), (lv_t*)lB, 16, 0, 0);
        __builtin_amdgcn_global_load_lds((gv_t*)(gB + 64 * KPAD + k0),
                                         (lv_t*)(lB + 64 * 32), 16, 0, 0);
        __syncthreads();

        bf16x8 bfr[4];
#pragma unroll
        for (int nt = 0; nt < 4; nt++)
            bfr[nt] = *(const bf16x8*)&Bs[(wn * 64 + nt * 16 + l15) * 32 + q * 8];
#pragma unroll
        for (int mt = 0; mt < 4; mt++) {
            bf16x8 afr = *(const bf16x8*)&As[(wm * 64 + mt * 16 + l15) * 32 + q * 8];
#pragma unroll
            for (int nt = 0; nt < 4; nt++)
                acc[mt][nt] = __builtin_amdgcn_mfma_f32_16x16x32_bf16(afr, bfr[nt],
                                                                      acc[mt][nt], 0, 0, 0);
        }
        __syncthreads();
    }
#pragma unroll
    for (int mt = 0; mt < 4; mt++) {
        int grow0 = rowBase + wm * 64 + mt * 16 + q * 4;
#pragma unroll
        for (int nt = 0; nt < 4; nt++) {
            int gcol = colBase + wn * 64 + nt * 16 + l15;
            if (gcol < ZXW) {
#pragma unroll
                for (int reg = 0; reg < 4; reg++) {
                    unsigned int u = bf16_rne(acc[mt][nt][reg]);
                    unsigned int partner = (unsigned int)__shfl_xor((int)u, 1, 64);
                    if ((l15 & 1) == 0)
                        *(unsigned int*)&Czx[(size_t)(grow0 + reg) * ZXW + gcol] =
                            u | (partner << 16);
                }
            } else if (gcol < NPROJ) {
                float bias = dt_bias[gcol - ZXW];
#pragma unroll
                for (int reg = 0; reg < 4; reg++) {
                    float v = acc[mt][nt][reg] + bias;
                    v = (v > 20.f) ? v : __logf(1.f + __expf(v));
                    dtp[(size_t)(grow0 + reg) * NHEADS + (gcol - ZXW)] = v;
                }
            }
        }
    }
}

// ---------------------------------------------------------------------------
// Kernel 2: conv — tiled depthwise conv4 + SiLU from bf16 zxbc (R4-proven).
// DSE: xc_bf only for B/C (cg>=8); xcT_bf only for x/B (cg<=8).
// ---------------------------------------------------------------------------
#define CT_IN_STR 68
#define CT_TR_STR 70
__global__ __launch_bounds__(256) void conv_kernel(const unsigned short* __restrict__ zxbc,
                                                   const float* __restrict__ conv_w,
                                                   const float* __restrict__ conv_b,
                                                   unsigned short* __restrict__ xc_bf,
                                                   unsigned short* __restrict__ xcT_bf) {
    const int b = blockIdx.x;
    const int t0 = blockIdx.z * 64;
    __shared__ float In[67 * CT_IN_STR];
    __shared__ unsigned short OutT[64 * CT_TR_STR];
    const int cg = blockIdx.y;
    const int tid = threadIdx.x;
    const int lane = tid & 63;
    const int w = tid >> 6;
    const int ch = cg * 64 + lane;

    for (int r = w; r < 67; r += 4) {
        int t = t0 - 3 + r;
        float v = (t >= 0 && t < SEQ)
                      ? bf2f(zxbc[(size_t)(b * SEQ + t) * ZXW + D_INNER + ch])
                      : 0.f;
        In[r * CT_IN_STR + lane] = v;
    }
    __syncthreads();
    const float w0 = conv_w[ch * 4 + 0], w1 = conv_w[ch * 4 + 1];
    const float w2 = conv_w[ch * 4 + 2], w3 = conv_w[ch * 4 + 3];
    const float bias = conv_b[ch];
    unsigned short vals[16];
#pragma unroll
    for (int i = 0; i < 16; i++) {
        int tt = w * 16 + i;
        float acc = fmaf(w3, In[(tt + 3) * CT_IN_STR + lane],
                    fmaf(w2, In[(tt + 2) * CT_IN_STR + lane],
                    fmaf(w1, In[(tt + 1) * CT_IN_STR + lane],
                    fmaf(w0, In[tt * CT_IN_STR + lane], bias))));
        float sv = silu_f(acc);
        unsigned short bv = (t0 + tt < SEQ) ? bf16_rne(sv) : (unsigned short)0;
        vals[i] = bv;
        OutT[lane * CT_TR_STR + tt] = bv;
    }
    if (cg >= 8) {  // only B (cg==8) and C (cg==9) are read from xc_bf
#pragma unroll
        for (int i = 0; i < 16; i++) {
            int tt = w * 16 + i;
            if (t0 + tt < SEQ)
                xc_bf[(size_t)(b * SEQ + t0 + tt) * D_XBC + ch] = vals[i];
        }
    }
    if (cg <= 8) {  // only x (cg<8) and B (cg==8) are read from xcT_bf
        __syncthreads();
        unsigned short* dstbase = xcT_bf + ((size_t)b * D_XBC + cg * 64) * TPAD + t0;
#pragma unroll
        for (int i = 0; i < 16; i++) {
            int c2 = w * 16 + i;
            dstbase[(size_t)c2 * TPAD + lane] = OutT[c2 * CT_TR_STR + lane];
        }
    }
}

// ---------------------------------------------------------------------------
// Kernel 3: scan_fused v4 — 8-wave (512-thread) version of the R8 structure.
// Wave w: t-row group wt = w>>1, nt-pair wn2 = w&1 (nt = wn2*2+j, j in 0,1).
// Per-wave MFMA/VALU work halves; waves/SIMD doubles 2->4 (same 38 KB LDS,
// 2 blocks/CU, all 512 blocks co-resident). T14 prefetch retained. Math
// order per element identical to R8 -> bitwise-identical output.
// ---------------------------------------------------------------------------
#define LSTR 72
__global__ __launch_bounds__(512) void scan_fused(const unsigned short* __restrict__ xc_bf,
                                                  const unsigned short* __restrict__ xcT_bf,
                                                  const float* __restrict__ dtp,
                                                  const float* __restrict__ A_log,
                                                  const float* __restrict__ Dvec,
                                                  unsigned short* __restrict__ yout_bf) {
    __shared__ unsigned short C_l[64 * LSTR];   // C, then (post-S3) BwT
    __shared__ unsigned short BP_l[64 * LSTR];  // B, then (post-S3) P
    __shared__ unsigned short XT_l[64 * LSTR];  // x^T
    __shared__ unsigned short H_l[64 * LSTR];   // h_{c-1} bf16 [p][n]
    __shared__ float cs_s[64], dts_s[64], fws_s[64];
    __shared__ float tot_s;

    const int bh = blockIdx.x;
    const int b = bh >> 3, h = bh & 7;
    const int tid = threadIdx.x;
    const int lane = tid & 63, w = tid >> 6;        // w in 0..7
    const int wt = w >> 1;                           // t-row group 0..3
    const int wn2 = w & 1;                           // nt-pair selector
    const int q = lane >> 4, l15 = lane & 15;
    const float A = -__expf(A_log[h]);
    const float Dh = Dvec[h];
    const int r = tid >> 3;                          // staging row 0..63
    const int c0 = (tid & 7) * 8;                    // staging col 0,8,..,56

    f32x4 h_acc[2] = {};  // rows p = wt*16+q*4+rr, cols n = (wn2*2+j)*16+l15

    // ---- prologue: dtp for all 4 chunks (w==0 lanes), named scalars ----
    float pdt0 = 0.f, pdt1 = 0.f, pdt2 = 0.f, pdt3 = 0.f;
    if (w == 0) {
        const float* dp = dtp + (size_t)(b * SEQ) * NHEADS + h;
        pdt0 = dp[(0 * 64 + lane) * NHEADS];
        pdt1 = dp[(1 * 64 + lane) * NHEADS];
        pdt2 = dp[(2 * 64 + lane) * NHEADS];
        if (192 + lane < SEQ) pdt3 = dp[(192 + lane) * NHEADS];
    }

    // ---- prologue: prefetch chunk 0 into registers (1 uint4 per array) ----
    uint4 pC, pB, pX, pbr;
    {
        const unsigned short* rowp = xc_bf + (size_t)(b * SEQ + r) * D_XBC;
        pC = *(const uint4*)&rowp[D_INNER + D_STATE + c0];
        pB = *(const uint4*)&rowp[D_INNER + c0];
        const unsigned short* xrow = xcT_bf + ((size_t)b * D_XBC + h * HEADDIM + r) * TPAD;
        pX = *(const uint4*)&xrow[c0];
        const unsigned short* brow = xcT_bf + ((size_t)b * D_XBC + D_INNER + r) * TPAD + c0;
        pbr = *(const uint4*)&brow[0];
    }

    for (int c = 0; c < 4; ++c) {
        const int t0 = c * 64;
        if (c > 0) __syncthreads();  // S0: prev-chunk LDS reads done before overwrite

        // ---- replay prefetched regs -> LDS ----
        *(uint4*)&C_l[r * LSTR + c0] = pC;
        *(uint4*)&BP_l[r * LSTR + c0] = pB;
        *(uint4*)&XT_l[r * LSTR + c0] = pX;
        const uint4 braw = pbr;  // keep for post-S3 Bw phase

        if (w == 0) {
            int t = lane;
            float dtv = (c == 0) ? pdt0 : (c == 1) ? pdt1 : (c == 2) ? pdt2 : pdt3;
            float csv = dtv * A;
#pragma unroll
            for (int o = 1; o < 64; o <<= 1) {
                float u = __shfl_up(csv, o, 64);
                if (lane >= o) csv += u;
            }
            float tot = readlane_f(csv, 63);
            cs_s[t] = csv;
            dts_s[t] = dtv;
            fws_s[t] = dtv * __expf(tot - csv);
            if (lane == 0) tot_s = tot;
        }
        __syncthreads();  // S1

        // ---- issue chunk c+1 prefetch (lands under the compute below) ----
        if (c < 3) {
            const int t1 = t0 + 64;
            if (t1 + r < SEQ) {
                const unsigned short* rowp = xc_bf + (size_t)(b * SEQ + t1 + r) * D_XBC;
                pC = *(const uint4*)&rowp[D_INNER + D_STATE + c0];
                pB = *(const uint4*)&rowp[D_INNER + c0];
            } else {
                uint4 z = {0, 0, 0, 0};
                pC = z; pB = z;
            }
            const unsigned short* xrow =
                xcT_bf + ((size_t)b * D_XBC + h * HEADDIM + r) * TPAD + t1;
            pX = *(const uint4*)&xrow[c0];
            const unsigned short* brow =
                xcT_bf + ((size_t)b * D_XBC + D_INNER + r) * TPAD + t1 + c0;
            pbr = *(const uint4*)&brow[0];
        }

        // G = C . B^T  and  y_inter = C . h_{c-1}^T  (2 nt per wave)
        f32x4 g[2] = {};
        f32x4 yi[2] = {};
#pragma unroll
        for (int k0 = 0; k0 < 64; k0 += 32) {
            bf16x8 ca = *(const bf16x8*)&C_l[(wt * 16 + l15) * LSTR + k0 + q * 8];
#pragma unroll
            for (int j = 0; j < 2; j++) {
                int nt = wn2 * 2 + j;
                bf16x8 bb = *(const bf16x8*)&BP_l[(nt * 16 + l15) * LSTR + k0 + q * 8];
                g[j] = __builtin_amdgcn_mfma_f32_16x16x32_bf16(ca, bb, g[j], 0, 0, 0);
            }
            if (c > 0) {
#pragma unroll
                for (int j = 0; j < 2; j++) {
                    int nt = wn2 * 2 + j;
                    bf16x8 hb = *(const bf16x8*)&H_l[(nt * 16 + l15) * LSTR + k0 + q * 8];
                    yi[j] = __builtin_amdgcn_mfma_f32_16x16x32_bf16(ca, hb, yi[j], 0, 0, 0);
                }
            }
        }
        __syncthreads();  // S3

        {   // C_l <- Bw (B^T row-scaled by fws); thread owns 8 contiguous t's
            unsigned short tmp[8];
            const unsigned short* rp = (const unsigned short*)&braw;
#pragma unroll
            for (int j = 0; j < 8; j++) tmp[j] = bf16_rne(bf2f(rp[j]) * fws_s[c0 + j]);
            *(uint4*)&C_l[r * LSTR + c0] = *(uint4*)&tmp[0];
        }
#pragma unroll
        for (int j = 0; j < 2; j++) {   // BP_l <- P
            int nt = wn2 * 2 + j;
#pragma unroll
            for (int rr = 0; rr < 4; rr++) {
                int t = wt * 16 + q * 4 + rr;
                int s = nt * 16 + l15;
                float pv = 0.f;
                if (s <= t) {
                    pv = g[j][rr] * __expf(cs_s[t] - cs_s[s]) * dts_s[s];
                    if (s == t) pv += Dh;
                }
                unsigned int u = bf16_rne(pv);
                unsigned int partner = (unsigned int)__shfl_xor((int)u, 1, 64);
                if ((l15 & 1) == 0)
                    *(unsigned int*)&BP_l[t * LSTR + nt * 16 + l15] = u | (partner << 16);
            }
        }
        __syncthreads();  // S4

        // y_intra = P . x^T
        f32x4 y[2] = {};
#pragma unroll
        for (int k0 = 0; k0 < 64; k0 += 32) {
            bf16x8 pa = *(const bf16x8*)&BP_l[(wt * 16 + l15) * LSTR + k0 + q * 8];
#pragma unroll
            for (int j = 0; j < 2; j++) {
                int nt = wn2 * 2 + j;
                bf16x8 xb = *(const bf16x8*)&XT_l[(nt * 16 + l15) * LSTR + k0 + q * 8];
                y[j] = __builtin_amdgcn_mfma_f32_16x16x32_bf16(pa, xb, y[j], 0, 0, 0);
            }
        }
        if (c < 3) {
            f32x4 st[2] = {};
#pragma unroll
            for (int k0 = 0; k0 < 64; k0 += 32) {
                bf16x8 xa = *(const bf16x8*)&XT_l[(wt * 16 + l15) * LSTR + k0 + q * 8];
#pragma unroll
                for (int j = 0; j < 2; j++) {
                    int nt = wn2 * 2 + j;
                    bf16x8 bwb = *(const bf16x8*)&C_l[(nt * 16 + l15) * LSTR + k0 + q * 8];
                    st[j] = __builtin_amdgcn_mfma_f32_16x16x32_bf16(xa, bwb, st[j], 0, 0, 0);
                }
            }
            const float decay = __expf(tot_s);
#pragma unroll
            for (int j = 0; j < 2; j++) {
                int nt = wn2 * 2 + j;
                h_acc[j] = st[j] + decay * h_acc[j];
#pragma unroll
                for (int rr = 0; rr < 4; rr++) {
                    unsigned int u = bf16_rne(h_acc[j][rr]);
                    unsigned int partner = (unsigned int)__shfl_xor((int)u, 1, 64);
                    if ((l15 & 1) == 0)
                        *(unsigned int*)&H_l[(wt * 16 + q * 4 + rr) * LSTR + nt * 16 + l15] =
                            u | (partner << 16);
                }
            }
        }
        // yout = y_intra + exp(cs_t) * y_inter  (single write, no RMW)
#pragma unroll
        for (int j = 0; j < 2; j++) {
            int nt = wn2 * 2 + j;
#pragma unroll
            for (int rr = 0; rr < 4; rr++) {
                int t = wt * 16 + q * 4 + rr;
                if (t0 + t < SEQ) {
                    int p = nt * 16 + l15;
                    float yv = y[j][rr];
                    if (c > 0) yv += __expf(cs_s[t]) * yi[j][rr];
                    unsigned int u = bf16_rne(yv);
                    unsigned int partner = (unsigned int)__shfl_xor((int)u, 1, 64);
                    if ((l15 & 1) == 0)
                        *(unsigned int*)&yout_bf[(size_t)(b * SEQ + t0 + t) * D_INNER +
                                                 h * HEADDIM + p] = u | (partner << 16);
                }
            }
        }
    }
}

// ---------------------------------------------------------------------------
// Kernel 4: gemm2_fused — out = selu( rms_r * ((y*silu(z)*norm_w) @ W^T) ).
// R2-proven 32-row/500-block version (grid must stay >= 2x CU count).
// ---------------------------------------------------------------------------
#define SA 40
__global__ __launch_bounds__(256) void gemm2_fused(const unsigned short* __restrict__ yout_bf,
                                                   const unsigned short* __restrict__ zxbc,
                                                   const unsigned short* __restrict__ Bt,
                                                   const float* __restrict__ norm_w,
                                                   float* __restrict__ out) {
    __shared__ unsigned short As2[32 * SA];
    __shared__ unsigned short Bs2[256 * SA];
    __shared__ float rms_s[32];
    const int tid = threadIdx.x;
    const int lane = tid & 63;
    const int wn = tid >> 6;               // wave -> 64-col slice
    const int q = lane >> 4, l15 = lane & 15;
    const int rowBase = blockIdx.x * 32;
    f32x4 acc[2][4] = {};

    const int tr = tid >> 3;               // staging row 0..31
    const int tk = (tid & 7) * 4;          // staging k-offset 0..28

    const unsigned short* yrow = yout_bf + (size_t)(rowBase + tr) * D_INNER + tk;
    const unsigned short* zrow = zxbc + (size_t)(rowBase + tr) * ZXW + tk;
    float ssq = 0.f;

    for (int k0 = 0; k0 < D_INNER; k0 += 32) {
        // ---- A: u = y*silu(z)*norm_w, accumulate g^2 ----
        uint2 yp = *(const uint2*)&yrow[k0];
        uint2 zp = *(const uint2*)&zrow[k0];
        float4 nw = *(const float4*)&norm_w[k0 + tk];
        const unsigned short* ys = (const unsigned short*)&yp;
        const unsigned short* zs = (const unsigned short*)&zp;
        float g0 = bf2f(ys[0]) * silu_f(bf2f(zs[0]));
        float g1 = bf2f(ys[1]) * silu_f(bf2f(zs[1]));
        float g2 = bf2f(ys[2]) * silu_f(bf2f(zs[2]));
        float g3 = bf2f(ys[3]) * silu_f(bf2f(zs[3]));
        ssq = fmaf(g0, g0, ssq);
        ssq = fmaf(g1, g1, ssq);
        ssq = fmaf(g2, g2, ssq);
        ssq = fmaf(g3, g3, ssq);
        uint2 pk;
        pk.x = pack2(g0 * nw.x, g1 * nw.y);
        pk.y = pack2(g2 * nw.z, g3 * nw.w);
        *(uint2*)&As2[tr * SA + tk] = pk;
        // ---- B: col `tid`, 32 k-shorts ----
        const unsigned short* brow = Bt + (size_t)tid * D_INNER + k0;
        *(uint4*)&Bs2[tid * SA + 0] = *(const uint4*)&brow[0];
        *(uint4*)&Bs2[tid * SA + 8] = *(const uint4*)&brow[8];
        *(uint4*)&Bs2[tid * SA + 16] = *(const uint4*)&brow[16];
        *(uint4*)&Bs2[tid * SA + 24] = *(const uint4*)&brow[24];
        __syncthreads();

        bf16x8 bfr[4];
#pragma unroll
        for (int nt = 0; nt < 4; nt++)
            bfr[nt] = *(const bf16x8*)&Bs2[(wn * 64 + nt * 16 + l15) * SA + q * 8];
#pragma unroll
        for (int mt = 0; mt < 2; mt++) {
            bf16x8 afr = *(const bf16x8*)&As2[(mt * 16 + l15) * SA + q * 8];
#pragma unroll
            for (int nt = 0; nt < 4; nt++)
                acc[mt][nt] = __builtin_amdgcn_mfma_f32_16x16x32_bf16(afr, bfr[nt],
                                                                      acc[mt][nt], 0, 0, 0);
        }
        __syncthreads();
    }
    // per-row rms: reduce ssq over the 8 lanes (tid&7) that share row tr
    ssq += __shfl_xor(ssq, 1, 64);
    ssq += __shfl_xor(ssq, 2, 64);
    ssq += __shfl_xor(ssq, 4, 64);
    if ((tid & 7) == 0) rms_s[tr] = rsqrtf(ssq * (1.f / 512.f) + 1e-5f);
    __syncthreads();

    const float SC = 1.0507009873554805f, AL = 1.6732632423543772f;
#pragma unroll
    for (int mt = 0; mt < 2; mt++) {
        int lrow0 = mt * 16 + q * 4;
#pragma unroll
        for (int nt = 0; nt < 4; nt++) {
            int gcol = wn * 64 + nt * 16 + l15;
            if (gcol < 240) {
#pragma unroll
                for (int reg = 0; reg < 4; reg++) {
                    float v = acc[mt][nt][reg] * rms_s[lrow0 + reg];
                    v = (v > 0.f) ? SC * v : SC * AL * (__expf(v) - 1.f);
                    out[(size_t)(rowBase + lrow0 + reg) * 240 + gcol] = v;
                }
            }
        }
    }
}

// ---------------------------------------------------------------------------
extern "C" void kernel_launch(void* const* d_in, const int* in_sizes, int n_in,
                              void* d_out, int out_size, void* d_ws, size_t ws_size,
                              hipStream_t stream) {
    const float* x = (const float*)d_in[0];
    const float* W_in = (const float*)d_in[1];
    const float* conv_w = (const float*)d_in[2];
    const float* conv_b = (const float*)d_in[3];
    const float* A_log = (const float*)d_in[4];
    const float* dt_bias = (const float*)d_in[5];
    const float* Dv = (const float*)d_in[6];
    const float* norm_w = (const float*)d_in[7];
    const float* W_out = (const float*)d_in[8];
    float* out = (float*)d_out;

    unsigned short* us = (unsigned short*)d_ws;
    unsigned short* zxbc_bf = us;                              // 16000*1152
    unsigned short* xc_bf = zxbc_bf + (size_t)ROWS * ZXW;      // 16000*640
    unsigned short* xcT_bf = xc_bf + (size_t)ROWS * D_XBC;     // 64*640*256
    unsigned short* yout_bf = xcT_bf + (size_t)BATCH * D_XBC * TPAD;  // 16000*512
    unsigned short* bt_bf = yout_bf + (size_t)ROWS * D_INNER;  // 1280*256
    unsigned short* wt_bf = bt_bf + (size_t)NPAD * KPAD;       // 256*512
    float* dtp = (float*)(wt_bf + (size_t)D_MODEL * D_INNER);  // 16000*8 f32
    unsigned short* a_bf = (unsigned short*)(dtp + (size_t)ROWS * NHEADS);  // 16000*256

    int cast_total = NA + NB + NW;
    cast_all_kernel<<<dim3((cast_total + 255) / 256), 256, 0, stream>>>(x, W_in, W_out,
                                                                        a_bf, bt_bf, wt_bf);

    gemm1_mfma<<<dim3(NPAD / 128, ROWS / 128), 256, 0, stream>>>(a_bf, bt_bf, dt_bias,
                                                                 zxbc_bf, dtp);

    conv_kernel<<<dim3(BATCH, 10, 4), 256, 0, stream>>>(zxbc_bf, conv_w, conv_b,
                                                        xc_bf, xcT_bf);

    scan_fused<<<dim3(BATCH * NHEADS), 512, 0, stream>>>(xc_bf, xcT_bf, dtp, A_log, Dv,
                                                         yout_bf);

    gemm2_fused<<<dim3(ROWS / 32), 256, 0, stream>>>(yout_bf, zxbc_bf, wt_bf, norm_w, out);
}

// Round 10
// 178.967 us; speedup vs baseline: 1.1237x; 1.0105x over previous
//
#include <hip/hip_runtime.h>
#include <cstdint>
#include <cstddef>

#define D_MODEL 256
#define D_STATE 64
#define HEADDIM 64
#define D_INNER 512
#define NHEADS 8
#define D_XBC 640
#define NPROJ 1160
#define ZXW 1152   /* bf16 zxbc row width (z + xBC) */
#define BATCH 64
#define SEQ 250
#define ROWS (BATCH * SEQ) /* 16000 */
#define KIN 240
#define KPAD 256
#define NPAD 1280  /* padded to 10x128 col-panels for the 128x128-tile gemm1 */
#define TPAD 256   /* t padded to 256 in xcT */

typedef __bf16 bf16x8 __attribute__((ext_vector_type(8)));
typedef float f32x4 __attribute__((ext_vector_type(4)));

typedef __attribute__((address_space(1))) const void gv_t;
typedef __attribute__((address_space(3))) void lv_t;

__device__ __forceinline__ float readlane_f(float v, int lane) {
    return __uint_as_float(__builtin_amdgcn_readlane(__float_as_uint(v), lane));
}
__device__ __forceinline__ float silu_f(float x) { return x * (1.f / (1.f + __expf(-x))); }
__device__ __forceinline__ unsigned short bf16_rne(float f) {
    unsigned int u = __float_as_uint(f);
    u += 0x7fff + ((u >> 16) & 1);
    return (unsigned short)(u >> 16);
}
__device__ __forceinline__ float bf2f(unsigned short u) {
    return __uint_as_float(((unsigned int)u) << 16);
}
__device__ __forceinline__ unsigned int pack2(float a, float b) {
    return (unsigned int)bf16_rne(a) | ((unsigned int)bf16_rne(b) << 16);
}

// ---------------------------------------------------------------------------
// Kernel 0: cast_all — x -> a_bf [16000][256], W_in -> bt_bf [1280][256] (T),
// W_out -> wt_bf [256][512] (T). One launch for all three.
// ---------------------------------------------------------------------------
#define NA (ROWS * KPAD)
#define NB (NPAD * KPAD)
#define NW (D_MODEL * D_INNER)
__global__ __launch_bounds__(256) void cast_all_kernel(const float* __restrict__ x,
                                                       const float* __restrict__ Win,
                                                       const float* __restrict__ Wout,
                                                       unsigned short* __restrict__ a_bf,
                                                       unsigned short* __restrict__ bt_bf,
                                                       unsigned short* __restrict__ wt_bf) {
    int idx = blockIdx.x * 256 + threadIdx.x;
    if (idx < NA) {
        int row = idx >> 8, c = idx & 255;
        float v = (c < KIN) ? x[row * KIN + c] : 0.f;
        a_bf[idx] = bf16_rne(v);
    } else if (idx < NA + NB) {
        int r = idx - NA;
        int n = r >> 8, k = r & 255;
        float v = (n < NPROJ && k < KIN) ? Win[k * NPROJ + n] : 0.f;
        bt_bf[r] = bf16_rne(v);
    } else if (idx < NA + NB + NW) {
        int r = idx - NA - NB;
        int n = r & 255, k = r >> 8;
        wt_bf[n * D_INNER + k] = bf16_rne(Wout[k * D_MODEL + n]);
    }
}

// ---------------------------------------------------------------------------
// Kernel 1: gemm1 — m97-structure: 128x128 tile, BK=32, linear LDS,
// global_load_lds width=16 staging. Grid 10 x 125 with bijective XCD-chunk
// swizzle (m204). dt cols (1152..1159) get bias+softplus fused in the
// epilogue -> dtp (f32). Cols >=1160 discarded.
// ---------------------------------------------------------------------------
__global__ __launch_bounds__(256) void gemm1_mfma(const unsigned short* __restrict__ A,
                                                  const unsigned short* __restrict__ Bt,
                                                  const float* __restrict__ dt_bias,
                                                  unsigned short* __restrict__ Czx,
                                                  float* __restrict__ dtp) {
    __shared__ unsigned short As[128 * 32];
    __shared__ unsigned short Bs[128 * 32];
    const int tid = threadIdx.x;
    const int lane = tid & 63, wave = tid >> 6;
    const int wm = wave >> 1, wn = wave & 1;
    const int q = lane >> 4, l15 = lane & 15;
    // ---- bijective XCD swizzle: nwg = 1250 = 8*156 + 2 ----
    const int lin = blockIdx.y * 10 + blockIdx.x;
    const int xcd = lin & 7, rank = lin >> 3;
    const int newid = (xcd < 2 ? xcd * 157 : 2 * 157 + (xcd - 2) * 156) + rank;
    const int by = newid / 10, bx = newid - by * 10;
    const int rowBase = by * 128, colBase = bx * 128;
    f32x4 acc[4][4] = {};

    const int sr = tid >> 2;          // staging row 0..63
    const int sc = (tid & 3) * 8;     // staging col (bf16) 0,8,16,24

    const unsigned short* gA = A + (size_t)(rowBase + sr) * KPAD + sc;
    const unsigned short* gB = Bt + (size_t)(colBase + sr) * KPAD + sc;
    unsigned short* lA = &As[sr * 32 + sc];   // wave-uniform base + lane*16B
    unsigned short* lB = &Bs[sr * 32 + sc];

    for (int k0 = 0; k0 < KPAD; k0 += 32) {
        __builtin_amdgcn_global_load_lds((gv_t*)(gA + k0), (lv_t*)lA, 16, 0, 0);
        __builtin_amdgcn_global_load_lds((gv_t*)(gA + 64 * KPAD + k0),
                                         (lv_t*)(lA + 64 * 32), 16, 0, 0);
        __builtin_amdgcn_global_load_lds((gv_t*)(gB + k0), (lv_t*)lB, 16, 0, 0);
        __builtin_amdgcn_global_load_lds((gv_t*)(gB + 64 * KPAD + k0),
                                         (lv_t*)(lB + 64 * 32), 16, 0, 0);
        __syncthreads();

        bf16x8 bfr[4];
#pragma unroll
        for (int nt = 0; nt < 4; nt++)
            bfr[nt] = *(const bf16x8*)&Bs[(wn * 64 + nt * 16 + l15) * 32 + q * 8];
#pragma unroll
        for (int mt = 0; mt < 4; mt++) {
            bf16x8 afr = *(const bf16x8*)&As[(wm * 64 + mt * 16 + l15) * 32 + q * 8];
#pragma unroll
            for (int nt = 0; nt < 4; nt++)
                acc[mt][nt] = __builtin_amdgcn_mfma_f32_16x16x32_bf16(afr, bfr[nt],
                                                                      acc[mt][nt], 0, 0, 0);
        }
        __syncthreads();
    }
#pragma unroll
    for (int mt = 0; mt < 4; mt++) {
        int grow0 = rowBase + wm * 64 + mt * 16 + q * 4;
#pragma unroll
        for (int nt = 0; nt < 4; nt++) {
            int gcol = colBase + wn * 64 + nt * 16 + l15;
            if (gcol < ZXW) {
#pragma unroll
                for (int reg = 0; reg < 4; reg++) {
                    unsigned int u = bf16_rne(acc[mt][nt][reg]);
                    unsigned int partner = (unsigned int)__shfl_xor((int)u, 1, 64);
                    if ((l15 & 1) == 0)
                        *(unsigned int*)&Czx[(size_t)(grow0 + reg) * ZXW + gcol] =
                            u | (partner << 16);
                }
            } else if (gcol < NPROJ) {
                float bias = dt_bias[gcol - ZXW];
#pragma unroll
                for (int reg = 0; reg < 4; reg++) {
                    float v = acc[mt][nt][reg] + bias;
                    v = (v > 20.f) ? v : __logf(1.f + __expf(v));
                    dtp[(size_t)(grow0 + reg) * NHEADS + (gcol - ZXW)] = v;
                }
            }
        }
    }
}

// ---------------------------------------------------------------------------
// Kernel 2: conv — tiled depthwise conv4 + SiLU from bf16 zxbc (R4-proven).
// DSE: xc_bf only for B/C (cg>=8); xcT_bf only for x/B (cg<=8).
// ---------------------------------------------------------------------------
#define CT_IN_STR 68
#define CT_TR_STR 70
__global__ __launch_bounds__(256) void conv_kernel(const unsigned short* __restrict__ zxbc,
                                                   const float* __restrict__ conv_w,
                                                   const float* __restrict__ conv_b,
                                                   unsigned short* __restrict__ xc_bf,
                                                   unsigned short* __restrict__ xcT_bf) {
    const int b = blockIdx.x;
    const int t0 = blockIdx.z * 64;
    __shared__ float In[67 * CT_IN_STR];
    __shared__ unsigned short OutT[64 * CT_TR_STR];
    const int cg = blockIdx.y;
    const int tid = threadIdx.x;
    const int lane = tid & 63;
    const int w = tid >> 6;
    const int ch = cg * 64 + lane;

    for (int r = w; r < 67; r += 4) {
        int t = t0 - 3 + r;
        float v = (t >= 0 && t < SEQ)
                      ? bf2f(zxbc[(size_t)(b * SEQ + t) * ZXW + D_INNER + ch])
                      : 0.f;
        In[r * CT_IN_STR + lane] = v;
    }
    __syncthreads();
    const float w0 = conv_w[ch * 4 + 0], w1 = conv_w[ch * 4 + 1];
    const float w2 = conv_w[ch * 4 + 2], w3 = conv_w[ch * 4 + 3];
    const float bias = conv_b[ch];
    unsigned short vals[16];
#pragma unroll
    for (int i = 0; i < 16; i++) {
        int tt = w * 16 + i;
        float acc = fmaf(w3, In[(tt + 3) * CT_IN_STR + lane],
                    fmaf(w2, In[(tt + 2) * CT_IN_STR + lane],
                    fmaf(w1, In[(tt + 1) * CT_IN_STR + lane],
                    fmaf(w0, In[tt * CT_IN_STR + lane], bias))));
        float sv = silu_f(acc);
        unsigned short bv = (t0 + tt < SEQ) ? bf16_rne(sv) : (unsigned short)0;
        vals[i] = bv;
        OutT[lane * CT_TR_STR + tt] = bv;
    }
    if (cg >= 8) {  // only B (cg==8) and C (cg==9) are read from xc_bf
#pragma unroll
        for (int i = 0; i < 16; i++) {
            int tt = w * 16 + i;
            if (t0 + tt < SEQ)
                xc_bf[(size_t)(b * SEQ + t0 + tt) * D_XBC + ch] = vals[i];
        }
    }
    if (cg <= 8) {  // only x (cg<8) and B (cg==8) are read from xcT_bf
        __syncthreads();
        unsigned short* dstbase = xcT_bf + ((size_t)b * D_XBC + cg * 64) * TPAD + t0;
#pragma unroll
        for (int i = 0; i < 16; i++) {
            int c2 = w * 16 + i;
            dstbase[(size_t)c2 * TPAD + lane] = OutT[c2 * CT_TR_STR + lane];
        }
    }
}

// ---------------------------------------------------------------------------
// Kernel 3: scan_fused v5 — 8-wave R9 structure + two latency fixes:
// (a) XCD-grouping bh swizzle: bh = (raw&7)*64 + (raw>>3) (bijective, 512=8*64)
//     so each XCD owns 8 consecutive b's with ALL 8 heads -> shared xc B/C and
//     xcT-B rows are fetched once per XCD L2 instead of 8x across XCDs.
// (b) S0 barrier removed via parity double-buffering of C/BP/XT + prescan
//     arrays: chunk c+1's replay writes buf[(c+1)&1] while chunk c's tail
//     MFMAs/stores still read buf[c&1]; S1 is the single ordering point.
//     H_l stays single-buffered (written pre-S1, read post-S1: ordered).
// 3 barriers/chunk. LDS ~66 KB -> still 2 blocks/CU (512 blocks co-resident).
// Math order per element identical to R9 -> bitwise-identical output.
// ---------------------------------------------------------------------------
#define LSTR 72
__global__ __launch_bounds__(512) void scan_fused(const unsigned short* __restrict__ xc_bf,
                                                  const unsigned short* __restrict__ xcT_bf,
                                                  const float* __restrict__ dtp,
                                                  const float* __restrict__ A_log,
                                                  const float* __restrict__ Dvec,
                                                  unsigned short* __restrict__ yout_bf) {
    __shared__ unsigned short C_l[2][64 * LSTR];   // C, then (post-S3) BwT
    __shared__ unsigned short BP_l[2][64 * LSTR];  // B, then (post-S3) P
    __shared__ unsigned short XT_l[2][64 * LSTR];  // x^T
    __shared__ unsigned short H_l[64 * LSTR];      // h_{c-1} bf16 [p][n]
    __shared__ float cs_s[2][64], dts_s[2][64], fws_s[2][64];
    __shared__ float tot_s[2];

    // ---- XCD-grouping swizzle: same-b blocks share an XCD's L2 ----
    const int bhRaw = blockIdx.x;
    const int bh = (bhRaw & 7) * 64 + (bhRaw >> 3);
    const int b = bh >> 3, h = bh & 7;
    const int tid = threadIdx.x;
    const int lane = tid & 63, w = tid >> 6;        // w in 0..7
    const int wt = w >> 1;                           // t-row group 0..3
    const int wn2 = w & 1;                           // nt-pair selector
    const int q = lane >> 4, l15 = lane & 15;
    const float A = -__expf(A_log[h]);
    const float Dh = Dvec[h];
    const int r = tid >> 3;                          // staging row 0..63
    const int c0 = (tid & 7) * 8;                    // staging col 0,8,..,56

    f32x4 h_acc[2] = {};  // rows p = wt*16+q*4+rr, cols n = (wn2*2+j)*16+l15

    // ---- prologue: dtp for all 4 chunks (w==0 lanes), named scalars ----
    float pdt0 = 0.f, pdt1 = 0.f, pdt2 = 0.f, pdt3 = 0.f;
    if (w == 0) {
        const float* dp = dtp + (size_t)(b * SEQ) * NHEADS + h;
        pdt0 = dp[(0 * 64 + lane) * NHEADS];
        pdt1 = dp[(1 * 64 + lane) * NHEADS];
        pdt2 = dp[(2 * 64 + lane) * NHEADS];
        if (192 + lane < SEQ) pdt3 = dp[(192 + lane) * NHEADS];
    }

    // ---- prologue: prefetch chunk 0 into registers (1 uint4 per array) ----
    uint4 pC, pB, pX, pbr;
    {
        const unsigned short* rowp = xc_bf + (size_t)(b * SEQ + r) * D_XBC;
        pC = *(const uint4*)&rowp[D_INNER + D_STATE + c0];
        pB = *(const uint4*)&rowp[D_INNER + c0];
        const unsigned short* xrow = xcT_bf + ((size_t)b * D_XBC + h * HEADDIM + r) * TPAD;
        pX = *(const uint4*)&xrow[c0];
        const unsigned short* brow = xcT_bf + ((size_t)b * D_XBC + D_INNER + r) * TPAD + c0;
        pbr = *(const uint4*)&brow[0];
    }

    for (int c = 0; c < 4; ++c) {
        const int t0 = c * 64;
        const int cur = c & 1;

        // ---- replay prefetched regs -> LDS buf[cur] (no S0: other parity
        //      still serves the previous chunk's tail reads) ----
        *(uint4*)&C_l[cur][r * LSTR + c0] = pC;
        *(uint4*)&BP_l[cur][r * LSTR + c0] = pB;
        *(uint4*)&XT_l[cur][r * LSTR + c0] = pX;
        const uint4 braw = pbr;  // keep for post-S3 Bw phase

        if (w == 0) {
            int t = lane;
            float dtv = (c == 0) ? pdt0 : (c == 1) ? pdt1 : (c == 2) ? pdt2 : pdt3;
            float csv = dtv * A;
#pragma unroll
            for (int o = 1; o < 64; o <<= 1) {
                float u = __shfl_up(csv, o, 64);
                if (lane >= o) csv += u;
            }
            float tot = readlane_f(csv, 63);
            cs_s[cur][t] = csv;
            dts_s[cur][t] = dtv;
            fws_s[cur][t] = dtv * __expf(tot - csv);
            if (lane == 0) tot_s[cur] = tot;
        }
        __syncthreads();  // S1: replay + prescan visible; prev chunk fully done

        // ---- issue chunk c+1 prefetch (lands under the compute below) ----
        if (c < 3) {
            const int t1 = t0 + 64;
            if (t1 + r < SEQ) {
                const unsigned short* rowp = xc_bf + (size_t)(b * SEQ + t1 + r) * D_XBC;
                pC = *(const uint4*)&rowp[D_INNER + D_STATE + c0];
                pB = *(const uint4*)&rowp[D_INNER + c0];
            } else {
                uint4 z = {0, 0, 0, 0};
                pC = z; pB = z;
            }
            const unsigned short* xrow =
                xcT_bf + ((size_t)b * D_XBC + h * HEADDIM + r) * TPAD + t1;
            pX = *(const uint4*)&xrow[c0];
            const unsigned short* brow =
                xcT_bf + ((size_t)b * D_XBC + D_INNER + r) * TPAD + t1 + c0;
            pbr = *(const uint4*)&brow[0];
        }

        // G = C . B^T  and  y_inter = C . h_{c-1}^T  (2 nt per wave)
        f32x4 g[2] = {};
        f32x4 yi[2] = {};
#pragma unroll
        for (int k0 = 0; k0 < 64; k0 += 32) {
            bf16x8 ca = *(const bf16x8*)&C_l[cur][(wt * 16 + l15) * LSTR + k0 + q * 8];
#pragma unroll
            for (int j = 0; j < 2; j++) {
                int nt = wn2 * 2 + j;
                bf16x8 bb = *(const bf16x8*)&BP_l[cur][(nt * 16 + l15) * LSTR + k0 + q * 8];
                g[j] = __builtin_amdgcn_mfma_f32_16x16x32_bf16(ca, bb, g[j], 0, 0, 0);
            }
            if (c > 0) {
#pragma unroll
                for (int j = 0; j < 2; j++) {
                    int nt = wn2 * 2 + j;
                    bf16x8 hb = *(const bf16x8*)&H_l[(nt * 16 + l15) * LSTR + k0 + q * 8];
                    yi[j] = __builtin_amdgcn_mfma_f32_16x16x32_bf16(ca, hb, yi[j], 0, 0, 0);
                }
            }
        }
        __syncthreads();  // S3: G reads done before C_l/BP_l overwrite

        {   // C_l <- Bw (B^T row-scaled by fws); thread owns 8 contiguous t's
            unsigned short tmp[8];
            const unsigned short* rp = (const unsigned short*)&braw;
#pragma unroll
            for (int j = 0; j < 8; j++) tmp[j] = bf16_rne(bf2f(rp[j]) * fws_s[cur][c0 + j]);
            *(uint4*)&C_l[cur][r * LSTR + c0] = *(uint4*)&tmp[0];
        }
#pragma unroll
        for (int j = 0; j < 2; j++) {   // BP_l <- P
            int nt = wn2 * 2 + j;
#pragma unroll
            for (int rr = 0; rr < 4; rr++) {
                int t = wt * 16 + q * 4 + rr;
                int s = nt * 16 + l15;
                float pv = 0.f;
                if (s <= t) {
                    pv = g[j][rr] * __expf(cs_s[cur][t] - cs_s[cur][s]) * dts_s[cur][s];
                    if (s == t) pv += Dh;
                }
                unsigned int u = bf16_rne(pv);
                unsigned int partner = (unsigned int)__shfl_xor((int)u, 1, 64);
                if ((l15 & 1) == 0)
                    *(unsigned int*)&BP_l[cur][t * LSTR + nt * 16 + l15] = u | (partner << 16);
            }
        }
        __syncthreads();  // S4: P/Bw ready

        // y_intra = P . x^T
        f32x4 y[2] = {};
#pragma unroll
        for (int k0 = 0; k0 < 64; k0 += 32) {
            bf16x8 pa = *(const bf16x8*)&BP_l[cur][(wt * 16 + l15) * LSTR + k0 + q * 8];
#pragma unroll
            for (int j = 0; j < 2; j++) {
                int nt = wn2 * 2 + j;
                bf16x8 xb = *(const bf16x8*)&XT_l[cur][(nt * 16 + l15) * LSTR + k0 + q * 8];
                y[j] = __builtin_amdgcn_mfma_f32_16x16x32_bf16(pa, xb, y[j], 0, 0, 0);
            }
        }
        if (c < 3) {
            f32x4 st[2] = {};
#pragma unroll
            for (int k0 = 0; k0 < 64; k0 += 32) {
                bf16x8 xa = *(const bf16x8*)&XT_l[cur][(wt * 16 + l15) * LSTR + k0 + q * 8];
#pragma unroll
                for (int j = 0; j < 2; j++) {
                    int nt = wn2 * 2 + j;
                    bf16x8 bwb = *(const bf16x8*)&C_l[cur][(nt * 16 + l15) * LSTR + k0 + q * 8];
                    st[j] = __builtin_amdgcn_mfma_f32_16x16x32_bf16(xa, bwb, st[j], 0, 0, 0);
                }
            }
            const float decay = __expf(tot_s[cur]);
#pragma unroll
            for (int j = 0; j < 2; j++) {
                int nt = wn2 * 2 + j;
                h_acc[j] = st[j] + decay * h_acc[j];
#pragma unroll
                for (int rr = 0; rr < 4; rr++) {
                    unsigned int u = bf16_rne(h_acc[j][rr]);
                    unsigned int partner = (unsigned int)__shfl_xor((int)u, 1, 64);
                    if ((l15 & 1) == 0)
                        *(unsigned int*)&H_l[(wt * 16 + q * 4 + rr) * LSTR + nt * 16 + l15] =
                            u | (partner << 16);
                }
            }
        }
        // yout = y_intra + exp(cs_t) * y_inter  (single write, no RMW)
#pragma unroll
        for (int j = 0; j < 2; j++) {
            int nt = wn2 * 2 + j;
#pragma unroll
            for (int rr = 0; rr < 4; rr++) {
                int t = wt * 16 + q * 4 + rr;
                if (t0 + t < SEQ) {
                    int p = nt * 16 + l15;
                    float yv = y[j][rr];
                    if (c > 0) yv += __expf(cs_s[cur][t]) * yi[j][rr];
                    unsigned int u = bf16_rne(yv);
                    unsigned int partner = (unsigned int)__shfl_xor((int)u, 1, 64);
                    if ((l15 & 1) == 0)
                        *(unsigned int*)&yout_bf[(size_t)(b * SEQ + t0 + t) * D_INNER +
                                                 h * HEADDIM + p] = u | (partner << 16);
                }
            }
        }
    }
}

// ---------------------------------------------------------------------------
// Kernel 4: gemm2_fused — out = selu( rms_r * ((y*silu(z)*norm_w) @ W^T) ).
// R2-proven 32-row/500-block version (grid must stay >= 2x CU count).
// ---------------------------------------------------------------------------
#define SA 40
__global__ __launch_bounds__(256) void gemm2_fused(const unsigned short* __restrict__ yout_bf,
                                                   const unsigned short* __restrict__ zxbc,
                                                   const unsigned short* __restrict__ Bt,
                                                   const float* __restrict__ norm_w,
                                                   float* __restrict__ out) {
    __shared__ unsigned short As2[32 * SA];
    __shared__ unsigned short Bs2[256 * SA];
    __shared__ float rms_s[32];
    const int tid = threadIdx.x;
    const int lane = tid & 63;
    const int wn = tid >> 6;               // wave -> 64-col slice
    const int q = lane >> 4, l15 = lane & 15;
    const int rowBase = blockIdx.x * 32;
    f32x4 acc[2][4] = {};

    const int tr = tid >> 3;               // staging row 0..31
    const int tk = (tid & 7) * 4;          // staging k-offset 0..28

    const unsigned short* yrow = yout_bf + (size_t)(rowBase + tr) * D_INNER + tk;
    const unsigned short* zrow = zxbc + (size_t)(rowBase + tr) * ZXW + tk;
    float ssq = 0.f;

    for (int k0 = 0; k0 < D_INNER; k0 += 32) {
        // ---- A: u = y*silu(z)*norm_w, accumulate g^2 ----
        uint2 yp = *(const uint2*)&yrow[k0];
        uint2 zp = *(const uint2*)&zrow[k0];
        float4 nw = *(const float4*)&norm_w[k0 + tk];
        const unsigned short* ys = (const unsigned short*)&yp;
        const unsigned short* zs = (const unsigned short*)&zp;
        float g0 = bf2f(ys[0]) * silu_f(bf2f(zs[0]));
        float g1 = bf2f(ys[1]) * silu_f(bf2f(zs[1]));
        float g2 = bf2f(ys[2]) * silu_f(bf2f(zs[2]));
        float g3 = bf2f(ys[3]) * silu_f(bf2f(zs[3]));
        ssq = fmaf(g0, g0, ssq);
        ssq = fmaf(g1, g1, ssq);
        ssq = fmaf(g2, g2, ssq);
        ssq = fmaf(g3, g3, ssq);
        uint2 pk;
        pk.x = pack2(g0 * nw.x, g1 * nw.y);
        pk.y = pack2(g2 * nw.z, g3 * nw.w);
        *(uint2*)&As2[tr * SA + tk] = pk;
        // ---- B: col `tid`, 32 k-shorts ----
        const unsigned short* brow = Bt + (size_t)tid * D_INNER + k0;
        *(uint4*)&Bs2[tid * SA + 0] = *(const uint4*)&brow[0];
        *(uint4*)&Bs2[tid * SA + 8] = *(const uint4*)&brow[8];
        *(uint4*)&Bs2[tid * SA + 16] = *(const uint4*)&brow[16];
        *(uint4*)&Bs2[tid * SA + 24] = *(const uint4*)&brow[24];
        __syncthreads();

        bf16x8 bfr[4];
#pragma unroll
        for (int nt = 0; nt < 4; nt++)
            bfr[nt] = *(const bf16x8*)&Bs2[(wn * 64 + nt * 16 + l15) * SA + q * 8];
#pragma unroll
        for (int mt = 0; mt < 2; mt++) {
            bf16x8 afr = *(const bf16x8*)&As2[(mt * 16 + l15) * SA + q * 8];
#pragma unroll
            for (int nt = 0; nt < 4; nt++)
                acc[mt][nt] = __builtin_amdgcn_mfma_f32_16x16x32_bf16(afr, bfr[nt],
                                                                      acc[mt][nt], 0, 0, 0);
        }
        __syncthreads();
    }
    // per-row rms: reduce ssq over the 8 lanes (tid&7) that share row tr
    ssq += __shfl_xor(ssq, 1, 64);
    ssq += __shfl_xor(ssq, 2, 64);
    ssq += __shfl_xor(ssq, 4, 64);
    if ((tid & 7) == 0) rms_s[tr] = rsqrtf(ssq * (1.f / 512.f) + 1e-5f);
    __syncthreads();

    const float SC = 1.0507009873554805f, AL = 1.6732632423543772f;
#pragma unroll
    for (int mt = 0; mt < 2; mt++) {
        int lrow0 = mt * 16 + q * 4;
#pragma unroll
        for (int nt = 0; nt < 4; nt++) {
            int gcol = wn * 64 + nt * 16 + l15;
            if (gcol < 240) {
#pragma unroll
                for (int reg = 0; reg < 4; reg++) {
                    float v = acc[mt][nt][reg] * rms_s[lrow0 + reg];
                    v = (v > 0.f) ? SC * v : SC * AL * (__expf(v) - 1.f);
                    out[(size_t)(rowBase + lrow0 + reg) * 240 + gcol] = v;
                }
            }
        }
    }
}

// ---------------------------------------------------------------------------
extern "C" void kernel_launch(void* const* d_in, const int* in_sizes, int n_in,
                              void* d_out, int out_size, void* d_ws, size_t ws_size,
                              hipStream_t stream) {
    const float* x = (const float*)d_in[0];
    const float* W_in = (const float*)d_in[1];
    const float* conv_w = (const float*)d_in[2];
    const float* conv_b = (const float*)d_in[3];
    const float* A_log = (const float*)d_in[4];
    const float* dt_bias = (const float*)d_in[5];
    const float* Dv = (const float*)d_in[6];
    const float* norm_w = (const float*)d_in[7];
    const float* W_out = (const float*)d_in[8];
    float* out = (float*)d_out;

    unsigned short* us = (unsigned short*)d_ws;
    unsigned short* zxbc_bf = us;                              // 16000*1152
    unsigned short* xc_bf = zxbc_bf + (size_t)ROWS * ZXW;      // 16000*640
    unsigned short* xcT_bf = xc_bf + (size_t)ROWS * D_XBC;     // 64*640*256
    unsigned short* yout_bf = xcT_bf + (size_t)BATCH * D_XBC * TPAD;  // 16000*512
    unsigned short* bt_bf = yout_bf + (size_t)ROWS * D_INNER;  // 1280*256
    unsigned short* wt_bf = bt_bf + (size_t)NPAD * KPAD;       // 256*512
    float* dtp = (float*)(wt_bf + (size_t)D_MODEL * D_INNER);  // 16000*8 f32
    unsigned short* a_bf = (unsigned short*)(dtp + (size_t)ROWS * NHEADS);  // 16000*256

    int cast_total = NA + NB + NW;
    cast_all_kernel<<<dim3((cast_total + 255) / 256), 256, 0, stream>>>(x, W_in, W_out,
                                                                        a_bf, bt_bf, wt_bf);

    gemm1_mfma<<<dim3(NPAD / 128, ROWS / 128), 256, 0, stream>>>(a_bf, bt_bf, dt_bias,
                                                                 zxbc_bf, dtp);

    conv_kernel<<<dim3(BATCH, 10, 4), 256, 0, stream>>>(zxbc_bf, conv_w, conv_b,
                                                        xc_bf, xcT_bf);

    scan_fused<<<dim3(BATCH * NHEADS), 512, 0, stream>>>(xc_bf, xcT_bf, dtp, A_log, Dv,
                                                         yout_bf);

    gemm2_fused<<<dim3(ROWS / 32), 256, 0, stream>>>(yout_bf, zxbc_bf, wt_bf, norm_w, out);
}

// Round 11
// 178.629 us; speedup vs baseline: 1.1259x; 1.0019x over previous
//
#include <hip/hip_runtime.h>
#include <cstdint>
#include <cstddef>

#define D_MODEL 256
#define D_STATE 64
#define HEADDIM 64
#define D_INNER 512
#define NHEADS 8
#define D_XBC 640
#define NPROJ 1160
#define ZXW 1152   /* bf16 zxbc row width (z + xBC) */
#define BATCH 64
#define SEQ 250
#define ROWS (BATCH * SEQ) /* 16000 */
#define KIN 240
#define KPAD 256
#define NPAD 1280  /* padded to 10x128 col-panels for the 128x128-tile gemm1 */
#define TPAD 256   /* t padded to 256 in xcT */

typedef __bf16 bf16x8 __attribute__((ext_vector_type(8)));
typedef float f32x4 __attribute__((ext_vector_type(4)));

typedef __attribute__((address_space(1))) const void gv_t;
typedef __attribute__((address_space(3))) void lv_t;

__device__ __forceinline__ float readlane_f(float v, int lane) {
    return __uint_as_float(__builtin_amdgcn_readlane(__float_as_uint(v), lane));
}
__device__ __forceinline__ float silu_f(float x) { return x * (1.f / (1.f + __expf(-x))); }
__device__ __forceinline__ unsigned short bf16_rne(float f) {
    unsigned int u = __float_as_uint(f);
    u += 0x7fff + ((u >> 16) & 1);
    return (unsigned short)(u >> 16);
}
__device__ __forceinline__ float bf2f(unsigned short u) {
    return __uint_as_float(((unsigned int)u) << 16);
}
__device__ __forceinline__ unsigned int pack2(float a, float b) {
    return (unsigned int)bf16_rne(a) | ((unsigned int)bf16_rne(b) << 16);
}

// ---------------------------------------------------------------------------
// Kernel 0: cast_all — x -> a_bf [16000][256], W_in -> bt_bf [1280][256] (T),
// W_out -> wt_bf [256][512] (T). One launch for all three.
// ---------------------------------------------------------------------------
#define NA (ROWS * KPAD)
#define NB (NPAD * KPAD)
#define NW (D_MODEL * D_INNER)
__global__ __launch_bounds__(256) void cast_all_kernel(const float* __restrict__ x,
                                                       const float* __restrict__ Win,
                                                       const float* __restrict__ Wout,
                                                       unsigned short* __restrict__ a_bf,
                                                       unsigned short* __restrict__ bt_bf,
                                                       unsigned short* __restrict__ wt_bf) {
    int idx = blockIdx.x * 256 + threadIdx.x;
    if (idx < NA) {
        int row = idx >> 8, c = idx & 255;
        float v = (c < KIN) ? x[row * KIN + c] : 0.f;
        a_bf[idx] = bf16_rne(v);
    } else if (idx < NA + NB) {
        int r = idx - NA;
        int n = r >> 8, k = r & 255;
        float v = (n < NPROJ && k < KIN) ? Win[k * NPROJ + n] : 0.f;
        bt_bf[r] = bf16_rne(v);
    } else if (idx < NA + NB + NW) {
        int r = idx - NA - NB;
        int n = r & 255, k = r >> 8;
        wt_bf[n * D_INNER + k] = bf16_rne(Wout[k * D_MODEL + n]);
    }
}

// ---------------------------------------------------------------------------
// Kernel 1: gemm1 — m97-structure: 128x128 tile, BK=32, linear LDS,
// global_load_lds width=16 staging. Grid 10 x 125 with bijective XCD-chunk
// swizzle (m204). dt cols (1152..1159) get bias+softplus fused in the
// epilogue -> dtp (f32). Cols >=1160 discarded.
// ---------------------------------------------------------------------------
__global__ __launch_bounds__(256) void gemm1_mfma(const unsigned short* __restrict__ A,
                                                  const unsigned short* __restrict__ Bt,
                                                  const float* __restrict__ dt_bias,
                                                  unsigned short* __restrict__ Czx,
                                                  float* __restrict__ dtp) {
    __shared__ unsigned short As[128 * 32];
    __shared__ unsigned short Bs[128 * 32];
    const int tid = threadIdx.x;
    const int lane = tid & 63, wave = tid >> 6;
    const int wm = wave >> 1, wn = wave & 1;
    const int q = lane >> 4, l15 = lane & 15;
    // ---- bijective XCD swizzle: nwg = 1250 = 8*156 + 2 ----
    const int lin = blockIdx.y * 10 + blockIdx.x;
    const int xcd = lin & 7, rank = lin >> 3;
    const int newid = (xcd < 2 ? xcd * 157 : 2 * 157 + (xcd - 2) * 156) + rank;
    const int by = newid / 10, bx = newid - by * 10;
    const int rowBase = by * 128, colBase = bx * 128;
    f32x4 acc[4][4] = {};

    const int sr = tid >> 2;          // staging row 0..63
    const int sc = (tid & 3) * 8;     // staging col (bf16) 0,8,16,24

    const unsigned short* gA = A + (size_t)(rowBase + sr) * KPAD + sc;
    const unsigned short* gB = Bt + (size_t)(colBase + sr) * KPAD + sc;
    unsigned short* lA = &As[sr * 32 + sc];   // wave-uniform base + lane*16B
    unsigned short* lB = &Bs[sr * 32 + sc];

    for (int k0 = 0; k0 < KPAD; k0 += 32) {
        __builtin_amdgcn_global_load_lds((gv_t*)(gA + k0), (lv_t*)lA, 16, 0, 0);
        __builtin_amdgcn_global_load_lds((gv_t*)(gA + 64 * KPAD + k0),
                                         (lv_t*)(lA + 64 * 32), 16, 0, 0);
        __builtin_amdgcn_global_load_lds((gv_t*)(gB + k0), (lv_t*)lB, 16, 0, 0);
        __builtin_amdgcn_global_load_lds((gv_t*)(gB + 64 * KPAD + k0),
                                         (lv_t*)(lB + 64 * 32), 16, 0, 0);
        __syncthreads();

        bf16x8 bfr[4];
#pragma unroll
        for (int nt = 0; nt < 4; nt++)
            bfr[nt] = *(const bf16x8*)&Bs[(wn * 64 + nt * 16 + l15) * 32 + q * 8];
#pragma unroll
        for (int mt = 0; mt < 4; mt++) {
            bf16x8 afr = *(const bf16x8*)&As[(wm * 64 + mt * 16 + l15) * 32 + q * 8];
#pragma unroll
            for (int nt = 0; nt < 4; nt++)
                acc[mt][nt] = __builtin_amdgcn_mfma_f32_16x16x32_bf16(afr, bfr[nt],
                                                                      acc[mt][nt], 0, 0, 0);
        }
        __syncthreads();
    }
#pragma unroll
    for (int mt = 0; mt < 4; mt++) {
        int grow0 = rowBase + wm * 64 + mt * 16 + q * 4;
#pragma unroll
        for (int nt = 0; nt < 4; nt++) {
            int gcol = colBase + wn * 64 + nt * 16 + l15;
            if (gcol < ZXW) {
#pragma unroll
                for (int reg = 0; reg < 4; reg++) {
                    unsigned int u = bf16_rne(acc[mt][nt][reg]);
                    unsigned int partner = (unsigned int)__shfl_xor((int)u, 1, 64);
                    if ((l15 & 1) == 0)
                        *(unsigned int*)&Czx[(size_t)(grow0 + reg) * ZXW + gcol] =
                            u | (partner << 16);
                }
            } else if (gcol < NPROJ) {
                float bias = dt_bias[gcol - ZXW];
#pragma unroll
                for (int reg = 0; reg < 4; reg++) {
                    float v = acc[mt][nt][reg] + bias;
                    v = (v > 20.f) ? v : __logf(1.f + __expf(v));
                    dtp[(size_t)(grow0 + reg) * NHEADS + (gcol - ZXW)] = v;
                }
            }
        }
    }
}

// ---------------------------------------------------------------------------
// Kernel 2: conv — tiled depthwise conv4 + SiLU from bf16 zxbc (R4-proven).
// DSE: xc_bf only for B/C (cg>=8); xcT_bf only for x/B (cg<=8).
// ---------------------------------------------------------------------------
#define CT_IN_STR 68
#define CT_TR_STR 70
__global__ __launch_bounds__(256) void conv_kernel(const unsigned short* __restrict__ zxbc,
                                                   const float* __restrict__ conv_w,
                                                   const float* __restrict__ conv_b,
                                                   unsigned short* __restrict__ xc_bf,
                                                   unsigned short* __restrict__ xcT_bf) {
    const int b = blockIdx.x;
    const int t0 = blockIdx.z * 64;
    __shared__ float In[67 * CT_IN_STR];
    __shared__ unsigned short OutT[64 * CT_TR_STR];
    const int cg = blockIdx.y;
    const int tid = threadIdx.x;
    const int lane = tid & 63;
    const int w = tid >> 6;
    const int ch = cg * 64 + lane;

    for (int r = w; r < 67; r += 4) {
        int t = t0 - 3 + r;
        float v = (t >= 0 && t < SEQ)
                      ? bf2f(zxbc[(size_t)(b * SEQ + t) * ZXW + D_INNER + ch])
                      : 0.f;
        In[r * CT_IN_STR + lane] = v;
    }
    __syncthreads();
    const float w0 = conv_w[ch * 4 + 0], w1 = conv_w[ch * 4 + 1];
    const float w2 = conv_w[ch * 4 + 2], w3 = conv_w[ch * 4 + 3];
    const float bias = conv_b[ch];
    unsigned short vals[16];
#pragma unroll
    for (int i = 0; i < 16; i++) {
        int tt = w * 16 + i;
        float acc = fmaf(w3, In[(tt + 3) * CT_IN_STR + lane],
                    fmaf(w2, In[(tt + 2) * CT_IN_STR + lane],
                    fmaf(w1, In[(tt + 1) * CT_IN_STR + lane],
                    fmaf(w0, In[tt * CT_IN_STR + lane], bias))));
        float sv = silu_f(acc);
        unsigned short bv = (t0 + tt < SEQ) ? bf16_rne(sv) : (unsigned short)0;
        vals[i] = bv;
        OutT[lane * CT_TR_STR + tt] = bv;
    }
    if (cg >= 8) {  // only B (cg==8) and C (cg==9) are read from xc_bf
#pragma unroll
        for (int i = 0; i < 16; i++) {
            int tt = w * 16 + i;
            if (t0 + tt < SEQ)
                xc_bf[(size_t)(b * SEQ + t0 + tt) * D_XBC + ch] = vals[i];
        }
    }
    if (cg <= 8) {  // only x (cg<8) and B (cg==8) are read from xcT_bf
        __syncthreads();
        unsigned short* dstbase = xcT_bf + ((size_t)b * D_XBC + cg * 64) * TPAD + t0;
#pragma unroll
        for (int i = 0; i < 16; i++) {
            int c2 = w * 16 + i;
            dstbase[(size_t)c2 * TPAD + lane] = OutT[c2 * CT_TR_STR + lane];
        }
    }
}

// ---------------------------------------------------------------------------
// Kernel 3: scan_fused v6 — R10 structure + two critical-path fixes:
// (a) prefetch issue moved from after-S1 to after-S4: hipcc drains vmcnt(0)
//     before every __syncthreads (m97), so loads issued before S3 were being
//     drained there. After S4 there is NO barrier until the replay that
//     consumes them -> the y/st MFMAs + stores genuinely cover the latency.
// (b) all 4 chunks' dt-prescans hoisted to the prologue (wave c computes
//     chunk c's cumsum/fws into cs_s[4][64] etc., +3 KB LDS) — removes the
//     serial 64-lane scan (6 dep shfl_up + exp) from every chunk's S1 path.
//     Write-once, read post-S1-of-chunk-0: race-free.
// Parity double-buffer of C/BP/XT and XCD-grouping bh swizzle retained.
// 3 barriers/chunk. Math order identical -> bitwise-identical output.
// ---------------------------------------------------------------------------
#define LSTR 72
__global__ __launch_bounds__(512) void scan_fused(const unsigned short* __restrict__ xc_bf,
                                                  const unsigned short* __restrict__ xcT_bf,
                                                  const float* __restrict__ dtp,
                                                  const float* __restrict__ A_log,
                                                  const float* __restrict__ Dvec,
                                                  unsigned short* __restrict__ yout_bf) {
    __shared__ unsigned short C_l[2][64 * LSTR];   // C, then (post-S3) BwT
    __shared__ unsigned short BP_l[2][64 * LSTR];  // B, then (post-S3) P
    __shared__ unsigned short XT_l[2][64 * LSTR];  // x^T
    __shared__ unsigned short H_l[64 * LSTR];      // h_{c-1} bf16 [p][n]
    __shared__ float cs_s[4][64], dts_s[4][64], fws_s[4][64];
    __shared__ float tot_s[4];

    // ---- XCD-grouping swizzle: same-b blocks share an XCD's L2 ----
    const int bhRaw = blockIdx.x;
    const int bh = (bhRaw & 7) * 64 + (bhRaw >> 3);
    const int b = bh >> 3, h = bh & 7;
    const int tid = threadIdx.x;
    const int lane = tid & 63, w = tid >> 6;        // w in 0..7
    const int wt = w >> 1;                           // t-row group 0..3
    const int wn2 = w & 1;                           // nt-pair selector
    const int q = lane >> 4, l15 = lane & 15;
    const float A = -__expf(A_log[h]);
    const float Dh = Dvec[h];
    const int r = tid >> 3;                          // staging row 0..63
    const int c0 = (tid & 7) * 8;                    // staging col 0,8,..,56

    f32x4 h_acc[2] = {};  // rows p = wt*16+q*4+rr, cols n = (wn2*2+j)*16+l15

    // ---- prologue: all 4 chunks' dt-prescans, wave c handles chunk c ----
    if (w < 4) {
        int t = lane;
        int gt = w * 64 + t;
        float dtv = (gt < SEQ) ? dtp[(size_t)(b * SEQ + gt) * NHEADS + h] : 0.f;
        float csv = dtv * A;
#pragma unroll
        for (int o = 1; o < 64; o <<= 1) {
            float u = __shfl_up(csv, o, 64);
            if (lane >= o) csv += u;
        }
        float tot = readlane_f(csv, 63);
        cs_s[w][t] = csv;
        dts_s[w][t] = dtv;
        fws_s[w][t] = dtv * __expf(tot - csv);
        if (lane == 0) tot_s[w] = tot;
    }

    // ---- prologue: prefetch chunk 0 into registers (1 uint4 per array) ----
    uint4 pC, pB, pX, pbr;
    {
        const unsigned short* rowp = xc_bf + (size_t)(b * SEQ + r) * D_XBC;
        pC = *(const uint4*)&rowp[D_INNER + D_STATE + c0];
        pB = *(const uint4*)&rowp[D_INNER + c0];
        const unsigned short* xrow = xcT_bf + ((size_t)b * D_XBC + h * HEADDIM + r) * TPAD;
        pX = *(const uint4*)&xrow[c0];
        const unsigned short* brow = xcT_bf + ((size_t)b * D_XBC + D_INNER + r) * TPAD + c0;
        pbr = *(const uint4*)&brow[0];
    }

    for (int c = 0; c < 4; ++c) {
        const int t0 = c * 64;
        const int cur = c & 1;

        // ---- replay prefetched regs -> LDS buf[cur] (no S0: other parity
        //      still serves the previous chunk's tail reads) ----
        *(uint4*)&C_l[cur][r * LSTR + c0] = pC;
        *(uint4*)&BP_l[cur][r * LSTR + c0] = pB;
        *(uint4*)&XT_l[cur][r * LSTR + c0] = pX;
        const uint4 braw = pbr;  // keep for post-S3 Bw phase

        __syncthreads();  // S1: replay (+ prologue prescan on c==0) visible

        // G = C . B^T  and  y_inter = C . h_{c-1}^T  (2 nt per wave)
        f32x4 g[2] = {};
        f32x4 yi[2] = {};
#pragma unroll
        for (int k0 = 0; k0 < 64; k0 += 32) {
            bf16x8 ca = *(const bf16x8*)&C_l[cur][(wt * 16 + l15) * LSTR + k0 + q * 8];
#pragma unroll
            for (int j = 0; j < 2; j++) {
                int nt = wn2 * 2 + j;
                bf16x8 bb = *(const bf16x8*)&BP_l[cur][(nt * 16 + l15) * LSTR + k0 + q * 8];
                g[j] = __builtin_amdgcn_mfma_f32_16x16x32_bf16(ca, bb, g[j], 0, 0, 0);
            }
            if (c > 0) {
#pragma unroll
                for (int j = 0; j < 2; j++) {
                    int nt = wn2 * 2 + j;
                    bf16x8 hb = *(const bf16x8*)&H_l[(nt * 16 + l15) * LSTR + k0 + q * 8];
                    yi[j] = __builtin_amdgcn_mfma_f32_16x16x32_bf16(ca, hb, yi[j], 0, 0, 0);
                }
            }
        }
        __syncthreads();  // S3: G reads done before C_l/BP_l overwrite

        {   // C_l <- Bw (B^T row-scaled by fws); thread owns 8 contiguous t's
            unsigned short tmp[8];
            const unsigned short* rp = (const unsigned short*)&braw;
#pragma unroll
            for (int j = 0; j < 8; j++) tmp[j] = bf16_rne(bf2f(rp[j]) * fws_s[c][c0 + j]);
            *(uint4*)&C_l[cur][r * LSTR + c0] = *(uint4*)&tmp[0];
        }
#pragma unroll
        for (int j = 0; j < 2; j++) {   // BP_l <- P
            int nt = wn2 * 2 + j;
#pragma unroll
            for (int rr = 0; rr < 4; rr++) {
                int t = wt * 16 + q * 4 + rr;
                int s = nt * 16 + l15;
                float pv = 0.f;
                if (s <= t) {
                    pv = g[j][rr] * __expf(cs_s[c][t] - cs_s[c][s]) * dts_s[c][s];
                    if (s == t) pv += Dh;
                }
                unsigned int u = bf16_rne(pv);
                unsigned int partner = (unsigned int)__shfl_xor((int)u, 1, 64);
                if ((l15 & 1) == 0)
                    *(unsigned int*)&BP_l[cur][t * LSTR + nt * 16 + l15] = u | (partner << 16);
            }
        }
        __syncthreads();  // S4: P/Bw ready

        // ---- issue chunk c+1 prefetch HERE: no barrier until the replay
        //      that consumes it -> y/st MFMAs + stores cover the latency ----
        if (c < 3) {
            const int t1 = t0 + 64;
            if (t1 + r < SEQ) {
                const unsigned short* rowp = xc_bf + (size_t)(b * SEQ + t1 + r) * D_XBC;
                pC = *(const uint4*)&rowp[D_INNER + D_STATE + c0];
                pB = *(const uint4*)&rowp[D_INNER + c0];
            } else {
                uint4 z = {0, 0, 0, 0};
                pC = z; pB = z;
            }
            const unsigned short* xrow =
                xcT_bf + ((size_t)b * D_XBC + h * HEADDIM + r) * TPAD + t1;
            pX = *(const uint4*)&xrow[c0];
            const unsigned short* brow =
                xcT_bf + ((size_t)b * D_XBC + D_INNER + r) * TPAD + t1 + c0;
            pbr = *(const uint4*)&brow[0];
        }

        // y_intra = P . x^T
        f32x4 y[2] = {};
#pragma unroll
        for (int k0 = 0; k0 < 64; k0 += 32) {
            bf16x8 pa = *(const bf16x8*)&BP_l[cur][(wt * 16 + l15) * LSTR + k0 + q * 8];
#pragma unroll
            for (int j = 0; j < 2; j++) {
                int nt = wn2 * 2 + j;
                bf16x8 xb = *(const bf16x8*)&XT_l[cur][(nt * 16 + l15) * LSTR + k0 + q * 8];
                y[j] = __builtin_amdgcn_mfma_f32_16x16x32_bf16(pa, xb, y[j], 0, 0, 0);
            }
        }
        if (c < 3) {
            f32x4 st[2] = {};
#pragma unroll
            for (int k0 = 0; k0 < 64; k0 += 32) {
                bf16x8 xa = *(const bf16x8*)&XT_l[cur][(wt * 16 + l15) * LSTR + k0 + q * 8];
#pragma unroll
                for (int j = 0; j < 2; j++) {
                    int nt = wn2 * 2 + j;
                    bf16x8 bwb = *(const bf16x8*)&C_l[cur][(nt * 16 + l15) * LSTR + k0 + q * 8];
                    st[j] = __builtin_amdgcn_mfma_f32_16x16x32_bf16(xa, bwb, st[j], 0, 0, 0);
                }
            }
            const float decay = __expf(tot_s[c]);
#pragma unroll
            for (int j = 0; j < 2; j++) {
                int nt = wn2 * 2 + j;
                h_acc[j] = st[j] + decay * h_acc[j];
#pragma unroll
                for (int rr = 0; rr < 4; rr++) {
                    unsigned int u = bf16_rne(h_acc[j][rr]);
                    unsigned int partner = (unsigned int)__shfl_xor((int)u, 1, 64);
                    if ((l15 & 1) == 0)
                        *(unsigned int*)&H_l[(wt * 16 + q * 4 + rr) * LSTR + nt * 16 + l15] =
                            u | (partner << 16);
                }
            }
        }
        // yout = y_intra + exp(cs_t) * y_inter  (single write, no RMW)
#pragma unroll
        for (int j = 0; j < 2; j++) {
            int nt = wn2 * 2 + j;
#pragma unroll
            for (int rr = 0; rr < 4; rr++) {
                int t = wt * 16 + q * 4 + rr;
                if (t0 + t < SEQ) {
                    int p = nt * 16 + l15;
                    float yv = y[j][rr];
                    if (c > 0) yv += __expf(cs_s[c][t]) * yi[j][rr];
                    unsigned int u = bf16_rne(yv);
                    unsigned int partner = (unsigned int)__shfl_xor((int)u, 1, 64);
                    if ((l15 & 1) == 0)
                        *(unsigned int*)&yout_bf[(size_t)(b * SEQ + t0 + t) * D_INNER +
                                                 h * HEADDIM + p] = u | (partner << 16);
                }
            }
        }
    }
}

// ---------------------------------------------------------------------------
// Kernel 4: gemm2_fused — out = selu( rms_r * ((y*silu(z)*norm_w) @ W^T) ).
// R2-proven 32-row/500-block version (grid must stay >= 2x CU count).
// ---------------------------------------------------------------------------
#define SA 40
__global__ __launch_bounds__(256) void gemm2_fused(const unsigned short* __restrict__ yout_bf,
                                                   const unsigned short* __restrict__ zxbc,
                                                   const unsigned short* __restrict__ Bt,
                                                   const float* __restrict__ norm_w,
                                                   float* __restrict__ out) {
    __shared__ unsigned short As2[32 * SA];
    __shared__ unsigned short Bs2[256 * SA];
    __shared__ float rms_s[32];
    const int tid = threadIdx.x;
    const int lane = tid & 63;
    const int wn = tid >> 6;               // wave -> 64-col slice
    const int q = lane >> 4, l15 = lane & 15;
    const int rowBase = blockIdx.x * 32;
    f32x4 acc[2][4] = {};

    const int tr = tid >> 3;               // staging row 0..31
    const int tk = (tid & 7) * 4;          // staging k-offset 0..28

    const unsigned short* yrow = yout_bf + (size_t)(rowBase + tr) * D_INNER + tk;
    const unsigned short* zrow = zxbc + (size_t)(rowBase + tr) * ZXW + tk;
    float ssq = 0.f;

    for (int k0 = 0; k0 < D_INNER; k0 += 32) {
        // ---- A: u = y*silu(z)*norm_w, accumulate g^2 ----
        uint2 yp = *(const uint2*)&yrow[k0];
        uint2 zp = *(const uint2*)&zrow[k0];
        float4 nw = *(const float4*)&norm_w[k0 + tk];
        const unsigned short* ys = (const unsigned short*)&yp;
        const unsigned short* zs = (const unsigned short*)&zp;
        float g0 = bf2f(ys[0]) * silu_f(bf2f(zs[0]));
        float g1 = bf2f(ys[1]) * silu_f(bf2f(zs[1]));
        float g2 = bf2f(ys[2]) * silu_f(bf2f(zs[2]));
        float g3 = bf2f(ys[3]) * silu_f(bf2f(zs[3]));
        ssq = fmaf(g0, g0, ssq);
        ssq = fmaf(g1, g1, ssq);
        ssq = fmaf(g2, g2, ssq);
        ssq = fmaf(g3, g3, ssq);
        uint2 pk;
        pk.x = pack2(g0 * nw.x, g1 * nw.y);
        pk.y = pack2(g2 * nw.z, g3 * nw.w);
        *(uint2*)&As2[tr * SA + tk] = pk;
        // ---- B: col `tid`, 32 k-shorts ----
        const unsigned short* brow = Bt + (size_t)tid * D_INNER + k0;
        *(uint4*)&Bs2[tid * SA + 0] = *(const uint4*)&brow[0];
        *(uint4*)&Bs2[tid * SA + 8] = *(const uint4*)&brow[8];
        *(uint4*)&Bs2[tid * SA + 16] = *(const uint4*)&brow[16];
        *(uint4*)&Bs2[tid * SA + 24] = *(const uint4*)&brow[24];
        __syncthreads();

        bf16x8 bfr[4];
#pragma unroll
        for (int nt = 0; nt < 4; nt++)
            bfr[nt] = *(const bf16x8*)&Bs2[(wn * 64 + nt * 16 + l15) * SA + q * 8];
#pragma unroll
        for (int mt = 0; mt < 2; mt++) {
            bf16x8 afr = *(const bf16x8*)&As2[(mt * 16 + l15) * SA + q * 8];
#pragma unroll
            for (int nt = 0; nt < 4; nt++)
                acc[mt][nt] = __builtin_amdgcn_mfma_f32_16x16x32_bf16(afr, bfr[nt],
                                                                      acc[mt][nt], 0, 0, 0);
        }
        __syncthreads();
    }
    // per-row rms: reduce ssq over the 8 lanes (tid&7) that share row tr
    ssq += __shfl_xor(ssq, 1, 64);
    ssq += __shfl_xor(ssq, 2, 64);
    ssq += __shfl_xor(ssq, 4, 64);
    if ((tid & 7) == 0) rms_s[tr] = rsqrtf(ssq * (1.f / 512.f) + 1e-5f);
    __syncthreads();

    const float SC = 1.0507009873554805f, AL = 1.6732632423543772f;
#pragma unroll
    for (int mt = 0; mt < 2; mt++) {
        int lrow0 = mt * 16 + q * 4;
#pragma unroll
        for (int nt = 0; nt < 4; nt++) {
            int gcol = wn * 64 + nt * 16 + l15;
            if (gcol < 240) {
#pragma unroll
                for (int reg = 0; reg < 4; reg++) {
                    float v = acc[mt][nt][reg] * rms_s[lrow0 + reg];
                    v = (v > 0.f) ? SC * v : SC * AL * (__expf(v) - 1.f);
                    out[(size_t)(rowBase + lrow0 + reg) * 240 + gcol] = v;
                }
            }
        }
    }
}

// ---------------------------------------------------------------------------
extern "C" void kernel_launch(void* const* d_in, const int* in_sizes, int n_in,
                              void* d_out, int out_size, void* d_ws, size_t ws_size,
                              hipStream_t stream) {
    const float* x = (const float*)d_in[0];
    const float* W_in = (const float*)d_in[1];
    const float* conv_w = (const float*)d_in[2];
    const float* conv_b = (const float*)d_in[3];
    const float* A_log = (const float*)d_in[4];
    const float* dt_bias = (const float*)d_in[5];
    const float* Dv = (const float*)d_in[6];
    const float* norm_w = (const float*)d_in[7];
    const float* W_out = (const float*)d_in[8];
    float* out = (float*)d_out;

    unsigned short* us = (unsigned short*)d_ws;
    unsigned short* zxbc_bf = us;                              // 16000*1152
    unsigned short* xc_bf = zxbc_bf + (size_t)ROWS * ZXW;      // 16000*640
    unsigned short* xcT_bf = xc_bf + (size_t)ROWS * D_XBC;     // 64*640*256
    unsigned short* yout_bf = xcT_bf + (size_t)BATCH * D_XBC * TPAD;  // 16000*512
    unsigned short* bt_bf = yout_bf + (size_t)ROWS * D_INNER;  // 1280*256
    unsigned short* wt_bf = bt_bf + (size_t)NPAD * KPAD;       // 256*512
    float* dtp = (float*)(wt_bf + (size_t)D_MODEL * D_INNER);  // 16000*8 f32
    unsigned short* a_bf = (unsigned short*)(dtp + (size_t)ROWS * NHEADS);  // 16000*256

    int cast_total = NA + NB + NW;
    cast_all_kernel<<<dim3((cast_total + 255) / 256), 256, 0, stream>>>(x, W_in, W_out,
                                                                        a_bf, bt_bf, wt_bf);

    gemm1_mfma<<<dim3(NPAD / 128, ROWS / 128), 256, 0, stream>>>(a_bf, bt_bf, dt_bias,
                                                                 zxbc_bf, dtp);

    conv_kernel<<<dim3(BATCH, 10, 4), 256, 0, stream>>>(zxbc_bf, conv_w, conv_b,
                                                        xc_bf, xcT_bf);

    scan_fused<<<dim3(BATCH * NHEADS), 512, 0, stream>>>(xc_bf, xcT_bf, dtp, A_log, Dv,
                                                         yout_bf);

    gemm2_fused<<<dim3(ROWS / 32), 256, 0, stream>>>(yout_bf, zxbc_bf, wt_bf, norm_w, out);
}